// Round 1
// baseline (3116.539 us; speedup 1.0000x reference)
//
#include <hip/hip_runtime.h>
#include <stdint.h>

#define D_FEAT 128
#define D_OUT  64

// ---------------------------------------------------------------------------
// threefry2x32 (JAX-compatible)
// ---------------------------------------------------------------------------
__device__ __forceinline__ void threefry2x32(uint32_t k0, uint32_t k1,
                                             uint32_t& x0, uint32_t& x1) {
  uint32_t k2 = k0 ^ k1 ^ 0x1BD11BDAu;
#define TF_ROT(r) { x0 += x1; x1 = (x1 << (r)) | (x1 >> (32 - (r))); x1 ^= x0; }
  x0 += k0; x1 += k1;
  TF_ROT(13) TF_ROT(15) TF_ROT(26) TF_ROT(6)
  x0 += k1; x1 += k2 + 1u;
  TF_ROT(17) TF_ROT(29) TF_ROT(16) TF_ROT(24)
  x0 += k2; x1 += k0 + 2u;
  TF_ROT(13) TF_ROT(15) TF_ROT(26) TF_ROT(6)
  x0 += k0; x1 += k1 + 3u;
  TF_ROT(17) TF_ROT(29) TF_ROT(16) TF_ROT(24)
  x0 += k1; x1 += k2 + 4u;
  TF_ROT(13) TF_ROT(15) TF_ROT(26) TF_ROT(6)
  x0 += k2; x1 += k0 + 5u;
#undef TF_ROT
}

// Dropout mask, JAX threefry_partitionable path:
// bits(i) = r0 ^ r1 of threefry2x32(key=(0,42), ctr=(0, i)); keep iff bits < 2^31
__global__ void mask_kernel(uint8_t* __restrict__ mask, long total) {
  long i = (long)blockIdx.x * blockDim.x + threadIdx.x;
  if (i >= total) return;
  uint32_t x0 = 0u, x1 = (uint32_t)i;
  threefry2x32(0u, 42u, x0, x1);
  uint32_t bits = x0 ^ x1;
  mask[i] = (uint8_t)((bits >> 31) ^ 1u);
}

// ---------------------------------------------------------------------------
// edge_index dtype detection: int64 rows => all odd u32 words are zero
// ---------------------------------------------------------------------------
__global__ void detect_kernel(const uint32_t* __restrict__ ei, int* __restrict__ flag) {
  uint32_t v = ei[2 * threadIdx.x + 1];
  unsigned long long nz = __ballot(v != 0u);
  if (threadIdx.x == 0) flag[0] = (nz == 0ull) ? 1 : 0;
}

__device__ __forceinline__ void load_edge(const void* ei, int is64, long E, long e,
                                          long& src, long& dst) {
  if (is64) {
    const long long* p = (const long long*)ei;
    src = (long)p[e]; dst = (long)p[E + e];
  } else {
    const int* p = (const int*)ei;
    src = (long)p[e]; dst = (long)p[E + e];
  }
}

// ---------------------------------------------------------------------------
// degree + reciprocal
// ---------------------------------------------------------------------------
__global__ void deg_kernel(const void* __restrict__ ei, const int* __restrict__ flag,
                           float* __restrict__ deg, long E) {
  const int is64 = flag[0];
  long stride = (long)gridDim.x * blockDim.x;
  for (long e = (long)blockIdx.x * blockDim.x + threadIdx.x; e < E; e += stride) {
    long src, dst;
    load_edge(ei, is64, E, e, src, dst);
    unsafeAtomicAdd(&deg[dst], 1.0f);
  }
}

__global__ void inv_kernel(float* __restrict__ deg, int N) {
  int n = blockIdx.x * blockDim.x + threadIdx.x;
  if (n < N) deg[n] = 1.0f / fmaxf(deg[n], 1.0f);
}

// ---------------------------------------------------------------------------
// scatter-add: one wave per edge, 2 floats per lane (128 features)
// ---------------------------------------------------------------------------
__global__ __launch_bounds__(256) void scatter_kernel(
    const float* __restrict__ feat, const void* __restrict__ ei,
    const int* __restrict__ flag, float* __restrict__ agg, long E) {
  const int is64 = flag[0];
  const int lane = threadIdx.x & 63;
  long wid = ((long)blockIdx.x * blockDim.x + threadIdx.x) >> 6;
  long nwaves = ((long)gridDim.x * blockDim.x) >> 6;
  for (long e = wid; e < E; e += nwaves) {
    long src, dst;
    load_edge(ei, is64, E, e, src, dst);
    const float2 v = *(const float2*)(feat + src * D_FEAT + lane * 2);
    float* a = agg + dst * D_FEAT + lane * 2;
    unsafeAtomicAdd(a, v.x);
    unsafeAtomicAdd(a + 1, v.y);
  }
}

// ---------------------------------------------------------------------------
// layer 1: h1d = dropout(relu((agg*inv)@W1_l + b1 + x@W1_r))
// block = 256 threads, 32 nodes per block
// ---------------------------------------------------------------------------
__global__ __launch_bounds__(256) void layer1_kernel(
    const float* __restrict__ x, const float* __restrict__ agg,
    const float* __restrict__ invd, const float* __restrict__ W1l,
    const float* __restrict__ W1r, const float* __restrict__ b1,
    const uint8_t* __restrict__ mask, float* __restrict__ h1d, int N) {
  __shared__ float sx[32][128];
  __shared__ float sa[32][128];
  const int nb = blockIdx.x * 32;
  for (int idx = threadIdx.x; idx < 32 * 128; idx += 256) {
    int nl = idx >> 7, k = idx & 127;
    int n = nb + nl;
    float xs = 0.f, as = 0.f;
    if (n < N) {
      xs = x[(long)n * 128 + k];
      as = agg[(long)n * 128 + k] * invd[n];
    }
    sx[nl][k] = xs;
    sa[nl][k] = as;
  }
  __syncthreads();
  const int j = threadIdx.x & 127;
  const int g = threadIdx.x >> 7;  // 0..1
  float acc[16];
#pragma unroll
  for (int i = 0; i < 16; i++) acc[i] = 0.f;
  for (int k = 0; k < 128; k++) {
    float wl = W1l[k * 128 + j];
    float wr = W1r[k * 128 + j];
#pragma unroll
    for (int i = 0; i < 16; i++) {
      int nl = g + 2 * i;
      acc[i] = fmaf(sa[nl][k], wl, acc[i]);
      acc[i] = fmaf(sx[nl][k], wr, acc[i]);
    }
  }
  float bb = b1[j];
#pragma unroll
  for (int i = 0; i < 16; i++) {
    int nl = g + 2 * i;
    int n = nb + nl;
    if (n < N) {
      float h = fmaxf(acc[i] + bb, 0.f);
      long fi = (long)n * 128 + j;
      h1d[fi] = mask[fi] ? 2.0f * h : 0.0f;
    }
  }
}

// ---------------------------------------------------------------------------
// layer 2 + log_softmax: out = logsm((agg2*inv)@W2_l + b2 + h1d@W2_r)
// block = 256 threads = 4 waves; each wave handles 4 nodes (64 cols each)
// ---------------------------------------------------------------------------
__global__ __launch_bounds__(256) void layer2_kernel(
    const float* __restrict__ h1d, const float* __restrict__ agg,
    const float* __restrict__ invd, const float* __restrict__ W2l,
    const float* __restrict__ W2r, const float* __restrict__ b2,
    float* __restrict__ out, int N) {
  __shared__ float sh[16][128];
  __shared__ float sa[16][128];
  const int nb = blockIdx.x * 16;
  for (int idx = threadIdx.x; idx < 16 * 128; idx += 256) {
    int nl = idx >> 7, k = idx & 127;
    int n = nb + nl;
    float hs = 0.f, as = 0.f;
    if (n < N) {
      hs = h1d[(long)n * 128 + k];
      as = agg[(long)n * 128 + k] * invd[n];
    }
    sh[nl][k] = hs;
    sa[nl][k] = as;
  }
  __syncthreads();
  const int j = threadIdx.x & 63;
  const int g = threadIdx.x >> 6;  // wave id 0..3
  float acc[4];
#pragma unroll
  for (int i = 0; i < 4; i++) acc[i] = 0.f;
  for (int k = 0; k < 128; k++) {
    float wl = W2l[k * 64 + j];
    float wr = W2r[k * 64 + j];
#pragma unroll
    for (int i = 0; i < 4; i++) {
      int nl = g + 4 * i;
      acc[i] = fmaf(sa[nl][k], wl, acc[i]);
      acc[i] = fmaf(sh[nl][k], wr, acc[i]);
    }
  }
  float bb = b2[j];
#pragma unroll
  for (int i = 0; i < 4; i++) {
    int nl = g + 4 * i;
    int n = nb + nl;
    if (n >= N) continue;
    float o = acc[i] + bb;
    float m = o;
#pragma unroll
    for (int off = 32; off > 0; off >>= 1) m = fmaxf(m, __shfl_xor(m, off));
    float e = expf(o - m);
    float s = e;
#pragma unroll
    for (int off = 32; off > 0; off >>= 1) s += __shfl_xor(s, off);
    out[(long)n * 64 + j] = o - m - logf(s);
  }
}

// ---------------------------------------------------------------------------
extern "C" void kernel_launch(void* const* d_in, const int* in_sizes, int n_in,
                              void* d_out, int out_size, void* d_ws, size_t ws_size,
                              hipStream_t stream) {
  const float* x   = (const float*)d_in[0];
  const void*  ei  = d_in[1];
  const float* W1l = (const float*)d_in[2];
  const float* b1  = (const float*)d_in[3];
  const float* W1r = (const float*)d_in[4];
  const float* W2l = (const float*)d_in[5];
  const float* b2  = (const float*)d_in[6];
  const float* W2r = (const float*)d_in[7];
  float* out = (float*)d_out;

  const int  N  = in_sizes[0] / D_FEAT;    // 100000
  const long E  = (long)in_sizes[1] / 2;   // 1600000
  const long NF = (long)N * D_FEAT;        // 12.8M

  char* ws = (char*)d_ws;
  size_t off = 0;
  auto alloc = [&](size_t bytes) -> void* {
    void* p = ws + off;
    off = (off + bytes + 255) & ~(size_t)255;
    return p;
  };
  float*   deg  = (float*)alloc(sizeof(float) * N);    // becomes inv_deg
  float*   agg  = (float*)alloc(sizeof(float) * NF);   // reused for both layers
  float*   h1d  = (float*)alloc(sizeof(float) * NF);
  uint8_t* mask = (uint8_t*)alloc((size_t)NF);
  int*     flag = (int*)alloc(sizeof(int));

  hipMemsetAsync(deg, 0, sizeof(float) * N, stream);
  hipMemsetAsync(agg, 0, sizeof(float) * NF, stream);

  detect_kernel<<<1, 64, 0, stream>>>((const uint32_t*)ei, flag);
  deg_kernel<<<4096, 256, 0, stream>>>(ei, flag, deg, E);
  inv_kernel<<<(N + 255) / 256, 256, 0, stream>>>(deg, N);
  mask_kernel<<<(int)((NF + 255) / 256), 256, 0, stream>>>(mask, NF);

  scatter_kernel<<<8192, 256, 0, stream>>>(x, ei, flag, agg, E);
  layer1_kernel<<<(N + 31) / 32, 256, 0, stream>>>(x, agg, deg, W1l, W1r, b1, mask, h1d, N);

  hipMemsetAsync(agg, 0, sizeof(float) * NF, stream);
  scatter_kernel<<<8192, 256, 0, stream>>>(h1d, ei, flag, agg, E);
  layer2_kernel<<<(N + 15) / 16, 256, 0, stream>>>(h1d, agg, deg, W2l, W2r, b2, out, N);
}

// Round 2
// 820.046 us; speedup vs baseline: 3.8004x; 3.8004x over previous
//
#include <hip/hip_runtime.h>
#include <stdint.h>

#define D_FEAT 128
#define D_OUT  64

// ---------------------------------------------------------------------------
// threefry2x32 (JAX-compatible)
// ---------------------------------------------------------------------------
__device__ __forceinline__ void threefry2x32(uint32_t k0, uint32_t k1,
                                             uint32_t& x0, uint32_t& x1) {
  uint32_t k2 = k0 ^ k1 ^ 0x1BD11BDAu;
#define TF_ROT(r) { x0 += x1; x1 = (x1 << (r)) | (x1 >> (32 - (r))); x1 ^= x0; }
  x0 += k0; x1 += k1;
  TF_ROT(13) TF_ROT(15) TF_ROT(26) TF_ROT(6)
  x0 += k1; x1 += k2 + 1u;
  TF_ROT(17) TF_ROT(29) TF_ROT(16) TF_ROT(24)
  x0 += k2; x1 += k0 + 2u;
  TF_ROT(13) TF_ROT(15) TF_ROT(26) TF_ROT(6)
  x0 += k0; x1 += k1 + 3u;
  TF_ROT(17) TF_ROT(29) TF_ROT(16) TF_ROT(24)
  x0 += k1; x1 += k2 + 4u;
  TF_ROT(13) TF_ROT(15) TF_ROT(26) TF_ROT(6)
  x0 += k2; x1 += k0 + 5u;
#undef TF_ROT
}

// ---------------------------------------------------------------------------
// edge_index dtype detection: int64 rows => all odd u32 words are zero
// ---------------------------------------------------------------------------
__global__ void detect_kernel(const uint32_t* __restrict__ ei, int* __restrict__ flag) {
  uint32_t v = ei[2 * threadIdx.x + 1];
  unsigned long long nz = __ballot(v != 0u);
  if (threadIdx.x == 0) flag[0] = (nz == 0ull) ? 1 : 0;
}

__device__ __forceinline__ void load_edge(const void* ei, int is64, long E, long e,
                                          long& src, long& dst) {
  if (is64) {
    const long long* p = (const long long*)ei;
    src = (long)p[e]; dst = (long)p[E + e];
  } else {
    const int* p = (const int*)ei;
    src = (long)p[e]; dst = (long)p[E + e];
  }
}

// ---------------------------------------------------------------------------
// CSR build: histogram -> 2-level exclusive scan -> fill (cursor atomics)
// ---------------------------------------------------------------------------
__global__ __launch_bounds__(256) void hist_kernel(
    const void* __restrict__ ei, const int* __restrict__ flag,
    int* __restrict__ cnt, long E) {
  const int is64 = flag[0];
  long e = (long)blockIdx.x * blockDim.x + threadIdx.x;
  if (e >= E) return;
  long src, dst;
  load_edge(ei, is64, E, e, src, dst);
  atomicAdd(&cnt[dst], 1);
}

// 1024 elements per block (256 threads x 4)
__global__ __launch_bounds__(256) void scanA_kernel(
    const int* __restrict__ cnt, int* __restrict__ rowptr,
    int* __restrict__ bsum, int N) {
  __shared__ int ts[256];
  int base = blockIdx.x * 1024 + threadIdx.x * 4;
  int v[4];
  int s = 0;
#pragma unroll
  for (int i = 0; i < 4; i++) {
    int idx = base + i;
    v[i] = (idx < N) ? cnt[idx] : 0;
    s += v[i];
  }
  ts[threadIdx.x] = s;
  __syncthreads();
  for (int off = 1; off < 256; off <<= 1) {
    int t = (threadIdx.x >= off) ? ts[threadIdx.x - off] : 0;
    __syncthreads();
    ts[threadIdx.x] += t;
    __syncthreads();
  }
  int excl = ts[threadIdx.x] - s;
#pragma unroll
  for (int i = 0; i < 4; i++) {
    int idx = base + i;
    if (idx < N) rowptr[idx] = excl;
    excl += v[i];
  }
  if (threadIdx.x == 255) bsum[blockIdx.x] = ts[255];
}

__global__ void scanB_kernel(int* __restrict__ bsum, int NB) {
  __shared__ int ts[128];
  int v = (threadIdx.x < NB) ? bsum[threadIdx.x] : 0;
  ts[threadIdx.x] = v;
  __syncthreads();
  for (int off = 1; off < 128; off <<= 1) {
    int t = (threadIdx.x >= off) ? ts[threadIdx.x - off] : 0;
    __syncthreads();
    ts[threadIdx.x] += t;
    __syncthreads();
  }
  if (threadIdx.x < NB) bsum[threadIdx.x] = ts[threadIdx.x] - v;
}

__global__ __launch_bounds__(256) void scanC_kernel(
    int* __restrict__ rowptr, const int* __restrict__ bsum, int N, int E) {
  int idx = blockIdx.x * blockDim.x + threadIdx.x;
  if (idx < N) rowptr[idx] += bsum[idx >> 10];
  if (idx == N) rowptr[N] = E;
}

__global__ __launch_bounds__(256) void fill_kernel(
    const void* __restrict__ ei, const int* __restrict__ flag,
    int* __restrict__ cur, int* __restrict__ col, long E) {
  const int is64 = flag[0];
  long e = (long)blockIdx.x * blockDim.x + threadIdx.x;
  if (e >= E) return;
  long src, dst;
  load_edge(ei, is64, E, e, src, dst);
  int pos = atomicAdd(&cur[dst], 1);
  col[pos] = (int)src;
}

__global__ __launch_bounds__(256) void inv_kernel(
    const int* __restrict__ rowptr, float* __restrict__ invd, int N) {
  int n = blockIdx.x * blockDim.x + threadIdx.x;
  if (n < N) {
    int d = rowptr[n + 1] - rowptr[n];
    invd[n] = 1.0f / (float)(d > 1 ? d : 1);
  }
}

// ---------------------------------------------------------------------------
// gather-style mean aggregation: one wave per node, 2 floats per lane
// ---------------------------------------------------------------------------
__global__ __launch_bounds__(256) void agg_kernel(
    const float* __restrict__ feat, const int* __restrict__ rowptr,
    const int* __restrict__ col, const float* __restrict__ invd,
    float* __restrict__ agg, int N) {
  const int lane = threadIdx.x & 63;
  int n = (int)(((long)blockIdx.x * blockDim.x + threadIdx.x) >> 6);
  if (n >= N) return;
  int beg = rowptr[n], end = rowptr[n + 1];
  float ax = 0.f, ay = 0.f;
  int e = beg;
  for (; e + 1 < end; e += 2) {
    int s0 = col[e], s1 = col[e + 1];
    float2 v0 = *(const float2*)(feat + (long)s0 * D_FEAT + lane * 2);
    float2 v1 = *(const float2*)(feat + (long)s1 * D_FEAT + lane * 2);
    ax += v0.x + v1.x;
    ay += v0.y + v1.y;
  }
  if (e < end) {
    int s0 = col[e];
    float2 v0 = *(const float2*)(feat + (long)s0 * D_FEAT + lane * 2);
    ax += v0.x;
    ay += v0.y;
  }
  float s = invd[n];
  float2 r;
  r.x = ax * s;
  r.y = ay * s;
  *(float2*)(agg + (long)n * D_FEAT + lane * 2) = r;
}

// ---------------------------------------------------------------------------
// layer 1: h1d = dropout(relu(agg@W1_l + b1 + x@W1_r)), threefry fused
// block = 256 threads, 32 nodes per block
// ---------------------------------------------------------------------------
__global__ __launch_bounds__(256) void layer1_kernel(
    const float* __restrict__ x, const float* __restrict__ agg,
    const float* __restrict__ W1l, const float* __restrict__ W1r,
    const float* __restrict__ b1, float* __restrict__ h1d, int N) {
  __shared__ float sx[32][128];
  __shared__ float sa[32][128];
  const int nb = blockIdx.x * 32;
  for (int idx = threadIdx.x; idx < 32 * 128; idx += 256) {
    int nl = idx >> 7, k = idx & 127;
    int n = nb + nl;
    float xs = 0.f, as = 0.f;
    if (n < N) {
      xs = x[(long)n * 128 + k];
      as = agg[(long)n * 128 + k];
    }
    sx[nl][k] = xs;
    sa[nl][k] = as;
  }
  __syncthreads();
  const int j = threadIdx.x & 127;
  const int g = threadIdx.x >> 7;  // 0..1
  float acc[16];
#pragma unroll
  for (int i = 0; i < 16; i++) acc[i] = 0.f;
  for (int k = 0; k < 128; k++) {
    float wl = W1l[k * 128 + j];
    float wr = W1r[k * 128 + j];
#pragma unroll
    for (int i = 0; i < 16; i++) {
      int nl = g + 2 * i;
      acc[i] = fmaf(sa[nl][k], wl, acc[i]);
      acc[i] = fmaf(sx[nl][k], wr, acc[i]);
    }
  }
  float bb = b1[j];
#pragma unroll
  for (int i = 0; i < 16; i++) {
    int nl = g + 2 * i;
    int n = nb + nl;
    if (n < N) {
      float h = fmaxf(acc[i] + bb, 0.f);
      uint32_t fi = (uint32_t)n * 128u + (uint32_t)j;
      uint32_t x0 = 0u, x1 = fi;
      threefry2x32(0u, 42u, x0, x1);
      bool keep = (((x0 ^ x1) >> 31) == 0u);
      h1d[fi] = keep ? 2.0f * h : 0.0f;
    }
  }
}

// ---------------------------------------------------------------------------
// layer 2 + log_softmax: out = logsm(agg2@W2_l + b2 + h1d@W2_r)
// block = 256 threads = 4 waves; each wave handles 4 nodes (64 cols each)
// ---------------------------------------------------------------------------
__global__ __launch_bounds__(256) void layer2_kernel(
    const float* __restrict__ h1d, const float* __restrict__ agg,
    const float* __restrict__ W2l, const float* __restrict__ W2r,
    const float* __restrict__ b2, float* __restrict__ out, int N) {
  __shared__ float sh[16][128];
  __shared__ float sa[16][128];
  const int nb = blockIdx.x * 16;
  for (int idx = threadIdx.x; idx < 16 * 128; idx += 256) {
    int nl = idx >> 7, k = idx & 127;
    int n = nb + nl;
    float hs = 0.f, as = 0.f;
    if (n < N) {
      hs = h1d[(long)n * 128 + k];
      as = agg[(long)n * 128 + k];
    }
    sh[nl][k] = hs;
    sa[nl][k] = as;
  }
  __syncthreads();
  const int j = threadIdx.x & 63;
  const int g = threadIdx.x >> 6;  // wave id 0..3
  float acc[4];
#pragma unroll
  for (int i = 0; i < 4; i++) acc[i] = 0.f;
  for (int k = 0; k < 128; k++) {
    float wl = W2l[k * 64 + j];
    float wr = W2r[k * 64 + j];
#pragma unroll
    for (int i = 0; i < 4; i++) {
      int nl = g + 4 * i;
      acc[i] = fmaf(sa[nl][k], wl, acc[i]);
      acc[i] = fmaf(sh[nl][k], wr, acc[i]);
    }
  }
  float bb = b2[j];
#pragma unroll
  for (int i = 0; i < 4; i++) {
    int nl = g + 4 * i;
    int n = nb + nl;
    if (n >= N) continue;
    float o = acc[i] + bb;
    float m = o;
#pragma unroll
    for (int off = 32; off > 0; off >>= 1) m = fmaxf(m, __shfl_xor(m, off));
    float e = expf(o - m);
    float s = e;
#pragma unroll
    for (int off = 32; off > 0; off >>= 1) s += __shfl_xor(s, off);
    out[(long)n * 64 + j] = o - m - logf(s);
  }
}

// ---------------------------------------------------------------------------
extern "C" void kernel_launch(void* const* d_in, const int* in_sizes, int n_in,
                              void* d_out, int out_size, void* d_ws, size_t ws_size,
                              hipStream_t stream) {
  const float* x   = (const float*)d_in[0];
  const void*  ei  = d_in[1];
  const float* W1l = (const float*)d_in[2];
  const float* b1  = (const float*)d_in[3];
  const float* W1r = (const float*)d_in[4];
  const float* W2l = (const float*)d_in[5];
  const float* b2  = (const float*)d_in[6];
  const float* W2r = (const float*)d_in[7];
  float* out = (float*)d_out;

  const int  N  = in_sizes[0] / D_FEAT;    // 100000
  const long E  = (long)in_sizes[1] / 2;   // 1600000
  const long NF = (long)N * D_FEAT;        // 12.8M

  char* ws = (char*)d_ws;
  size_t off = 0;
  auto alloc = [&](size_t bytes) -> void* {
    void* p = ws + off;
    off = (off + bytes + 255) & ~(size_t)255;
    return p;
  };
  int*   cnt    = (int*)alloc(sizeof(int) * N);
  int*   rowptr = (int*)alloc(sizeof(int) * (N + 1));
  int*   cur    = (int*)alloc(sizeof(int) * N);
  int*   bsum   = (int*)alloc(sizeof(int) * 256);
  int*   col    = (int*)alloc(sizeof(int) * E);
  float* invd   = (float*)alloc(sizeof(float) * N);
  float* agg    = (float*)alloc(sizeof(float) * NF);
  float* h1d    = (float*)alloc(sizeof(float) * NF);
  int*   flag   = (int*)alloc(sizeof(int));

  const int NB = (N + 1023) / 1024;  // 98 scan blocks

  hipMemsetAsync(cnt, 0, sizeof(int) * N, stream);

  detect_kernel<<<1, 64, 0, stream>>>((const uint32_t*)ei, flag);
  hist_kernel<<<(int)((E + 255) / 256), 256, 0, stream>>>(ei, flag, cnt, E);
  scanA_kernel<<<NB, 256, 0, stream>>>(cnt, rowptr, bsum, N);
  scanB_kernel<<<1, 128, 0, stream>>>(bsum, NB);
  scanC_kernel<<<(N + 256) / 256, 256, 0, stream>>>(rowptr, bsum, N, (int)E);
  hipMemcpyAsync(cur, rowptr, sizeof(int) * N, hipMemcpyDeviceToDevice, stream);
  fill_kernel<<<(int)((E + 255) / 256), 256, 0, stream>>>(ei, flag, cur, col, E);
  inv_kernel<<<(N + 255) / 256, 256, 0, stream>>>(rowptr, invd, N);

  const int aggBlocks = (int)(((long)N * 64 + 255) / 256);
  agg_kernel<<<aggBlocks, 256, 0, stream>>>(x, rowptr, col, invd, agg, N);
  layer1_kernel<<<(N + 31) / 32, 256, 0, stream>>>(x, agg, W1l, W1r, b1, h1d, N);

  agg_kernel<<<aggBlocks, 256, 0, stream>>>(h1d, rowptr, col, invd, agg, N);
  layer2_kernel<<<(N + 15) / 16, 256, 0, stream>>>(h1d, agg, W2l, W2r, b2, out, N);
}

// Round 3
// 539.272 us; speedup vs baseline: 5.7792x; 1.5207x over previous
//
#include <hip/hip_runtime.h>
#include <stdint.h>

#define D_FEAT 128
#define D_OUT  64

typedef __attribute__((ext_vector_type(8))) short short8;   // 8 bf16 (4 VGPRs)
typedef __attribute__((ext_vector_type(4))) float f32x4;

// ---------------------------------------------------------------------------
// helpers
// ---------------------------------------------------------------------------
__device__ __forceinline__ ushort f2bf(float f) {            // RNE f32->bf16
  uint32_t u = __float_as_uint(f);
  return (ushort)((u + 0x7FFFu + ((u >> 16) & 1u)) >> 16);
}
__device__ __forceinline__ float bfhi2f(uint32_t v) { return __uint_as_float(v & 0xFFFF0000u); }
__device__ __forceinline__ float bflo2f(uint32_t v) { return __uint_as_float(v << 16); }

__device__ __forceinline__ void threefry2x32(uint32_t k0, uint32_t k1,
                                             uint32_t& x0, uint32_t& x1) {
  uint32_t k2 = k0 ^ k1 ^ 0x1BD11BDAu;
#define TF_ROT(r) { x0 += x1; x1 = (x1 << (r)) | (x1 >> (32 - (r))); x1 ^= x0; }
  x0 += k0; x1 += k1;
  TF_ROT(13) TF_ROT(15) TF_ROT(26) TF_ROT(6)
  x0 += k1; x1 += k2 + 1u;
  TF_ROT(17) TF_ROT(29) TF_ROT(16) TF_ROT(24)
  x0 += k2; x1 += k0 + 2u;
  TF_ROT(13) TF_ROT(15) TF_ROT(26) TF_ROT(6)
  x0 += k0; x1 += k1 + 3u;
  TF_ROT(17) TF_ROT(29) TF_ROT(16) TF_ROT(24)
  x0 += k1; x1 += k2 + 4u;
  TF_ROT(13) TF_ROT(15) TF_ROT(26) TF_ROT(6)
  x0 += k2; x1 += k0 + 5u;
#undef TF_ROT
}

// ---------------------------------------------------------------------------
// edge_index dtype detection: int64 rows => all odd u32 words are zero
// ---------------------------------------------------------------------------
__global__ void detect_kernel(const uint32_t* __restrict__ ei, int* __restrict__ flag) {
  uint32_t v = ei[2 * threadIdx.x + 1];
  unsigned long long nz = __ballot(v != 0u);
  if (threadIdx.x == 0) flag[0] = (nz == 0ull) ? 1 : 0;
}

__device__ __forceinline__ void load_edge(const void* ei, int is64, long E, long e,
                                          long& src, long& dst) {
  if (is64) {
    const long long* p = (const long long*)ei;
    src = (long)p[e]; dst = (long)p[E + e];
  } else {
    const int* p = (const int*)ei;
    src = (long)p[e]; dst = (long)p[E + e];
  }
}

// ---------------------------------------------------------------------------
// input conversions / weight packing
// ---------------------------------------------------------------------------
__global__ __launch_bounds__(256) void convx_kernel(
    const float4* __restrict__ x, ushort* __restrict__ xb, long n4) {
  long i = (long)blockIdx.x * blockDim.x + threadIdx.x;
  if (i >= n4) return;
  float4 v = x[i];
  ushort4 o = {f2bf(v.x), f2bf(v.y), f2bf(v.z), f2bf(v.w)};
  *(ushort4*)(xb + i * 4) = o;
}

// w1t[j][k] = bf16(k<128 ? W1l[k][j] : W1r[k-128][j]),  j<128, k<256
__global__ __launch_bounds__(256) void packw1_kernel(
    const float* __restrict__ Wl, const float* __restrict__ Wr,
    ushort* __restrict__ wt) {
  int idx = blockIdx.x * blockDim.x + threadIdx.x;   // 128*256
  if (idx >= 128 * 256) return;
  int j = idx >> 8, k = idx & 255;
  float v = (k < 128) ? Wl[k * 128 + j] : Wr[(k - 128) * 128 + j];
  wt[j * 256 + k] = f2bf(v);
}

// w2t[j][k] = bf16(k<128 ? W2l[k][j] : W2r[k-128][j]),  j<64, k<256
__global__ __launch_bounds__(256) void packw2_kernel(
    const float* __restrict__ Wl, const float* __restrict__ Wr,
    ushort* __restrict__ wt) {
  int idx = blockIdx.x * blockDim.x + threadIdx.x;   // 64*256
  if (idx >= 64 * 256) return;
  int j = idx >> 8, k = idx & 255;
  float v = (k < 128) ? Wl[k * 64 + j] : Wr[(k - 128) * 64 + j];
  wt[j * 256 + k] = f2bf(v);
}

// ---------------------------------------------------------------------------
// CSR build: histogram -> 2-level exclusive scan -> fill (cursor atomics)
// ---------------------------------------------------------------------------
__global__ __launch_bounds__(256) void hist_kernel(
    const void* __restrict__ ei, const int* __restrict__ flag,
    int* __restrict__ cnt, long E) {
  const int is64 = flag[0];
  long e = (long)blockIdx.x * blockDim.x + threadIdx.x;
  if (e >= E) return;
  long src, dst;
  load_edge(ei, is64, E, e, src, dst);
  atomicAdd(&cnt[dst], 1);
}

__global__ __launch_bounds__(256) void scanA_kernel(
    const int* __restrict__ cnt, int* __restrict__ rowptr,
    int* __restrict__ bsum, int N) {
  __shared__ int ts[256];
  int base = blockIdx.x * 1024 + threadIdx.x * 4;
  int v[4];
  int s = 0;
#pragma unroll
  for (int i = 0; i < 4; i++) {
    int idx = base + i;
    v[i] = (idx < N) ? cnt[idx] : 0;
    s += v[i];
  }
  ts[threadIdx.x] = s;
  __syncthreads();
  for (int off = 1; off < 256; off <<= 1) {
    int t = (threadIdx.x >= off) ? ts[threadIdx.x - off] : 0;
    __syncthreads();
    ts[threadIdx.x] += t;
    __syncthreads();
  }
  int excl = ts[threadIdx.x] - s;
#pragma unroll
  for (int i = 0; i < 4; i++) {
    int idx = base + i;
    if (idx < N) rowptr[idx] = excl;
    excl += v[i];
  }
  if (threadIdx.x == 255) bsum[blockIdx.x] = ts[255];
}

__global__ void scanB_kernel(int* __restrict__ bsum, int NB) {
  __shared__ int ts[128];
  int v = (threadIdx.x < NB) ? bsum[threadIdx.x] : 0;
  ts[threadIdx.x] = v;
  __syncthreads();
  for (int off = 1; off < 128; off <<= 1) {
    int t = (threadIdx.x >= off) ? ts[threadIdx.x - off] : 0;
    __syncthreads();
    ts[threadIdx.x] += t;
    __syncthreads();
  }
  if (threadIdx.x < NB) bsum[threadIdx.x] = ts[threadIdx.x] - v;
}

__global__ __launch_bounds__(256) void scanC_kernel(
    int* __restrict__ rowptr, const int* __restrict__ bsum, int N, int E) {
  int idx = blockIdx.x * blockDim.x + threadIdx.x;
  if (idx < N) rowptr[idx] += bsum[idx >> 10];
  if (idx == N) rowptr[N] = E;
}

__global__ __launch_bounds__(256) void fill_kernel(
    const void* __restrict__ ei, const int* __restrict__ flag,
    int* __restrict__ cur, int* __restrict__ col, long E) {
  const int is64 = flag[0];
  long e = (long)blockIdx.x * blockDim.x + threadIdx.x;
  if (e >= E) return;
  long src, dst;
  load_edge(ei, is64, E, e, src, dst);
  int pos = atomicAdd(&cur[dst], 1);
  col[pos] = (int)src;
}

__global__ __launch_bounds__(256) void inv_kernel(
    const int* __restrict__ rowptr, float* __restrict__ invd, int N) {
  int n = blockIdx.x * blockDim.x + threadIdx.x;
  if (n < N) {
    int d = rowptr[n + 1] - rowptr[n];
    invd[n] = 1.0f / (float)(d > 1 ? d : 1);
  }
}

// ---------------------------------------------------------------------------
// gather-style mean aggregation (bf16 in, fp32 accum, bf16 out)
// one wave per node, 2 bf16 (4 B) per lane
// ---------------------------------------------------------------------------
__global__ __launch_bounds__(256) void agg_kernel(
    const ushort* __restrict__ featb, const int* __restrict__ rowptr,
    const int* __restrict__ col, const float* __restrict__ invd,
    ushort* __restrict__ aggb, int N) {
  const int lane = threadIdx.x & 63;
  int n = (int)(((long)blockIdx.x * blockDim.x + threadIdx.x) >> 6);
  if (n >= N) return;
  int beg = rowptr[n], end = rowptr[n + 1];
  float ax = 0.f, ay = 0.f;
  int e = beg;
  for (; e + 1 < end; e += 2) {
    int s0 = col[e], s1 = col[e + 1];
    uint32_t v0 = *(const uint32_t*)(featb + (long)s0 * D_FEAT + lane * 2);
    uint32_t v1 = *(const uint32_t*)(featb + (long)s1 * D_FEAT + lane * 2);
    ax += bflo2f(v0) + bflo2f(v1);
    ay += bfhi2f(v0) + bfhi2f(v1);
  }
  if (e < end) {
    uint32_t v0 = *(const uint32_t*)(featb + (long)col[e] * D_FEAT + lane * 2);
    ax += bflo2f(v0);
    ay += bfhi2f(v0);
  }
  float sc = invd[n];
  uint32_t o = (uint32_t)f2bf(ax * sc) | ((uint32_t)f2bf(ay * sc) << 16);
  *(uint32_t*)(aggb + (long)n * D_FEAT + lane * 2) = o;
}

// ---------------------------------------------------------------------------
// layer 1 (MFMA): h1d = bf16(dropout(relu([agg|x]@[W1l;W1r] + b1)))
// block = 256 = 4 waves; wave computes 16 nodes x 128 cols
// A: lane holds row (lane&15), k = 8*(lane>>4)+i ; B same k, col=lane&15
// D: col = lane&15, row = 4*(lane>>4)+reg   [m89-verified]
// ---------------------------------------------------------------------------
__global__ __launch_bounds__(256) void layer1_kernel(
    const ushort* __restrict__ aggb, const ushort* __restrict__ xb,
    const ushort* __restrict__ w1t, const float* __restrict__ b1,
    ushort* __restrict__ h1d, int N) {
  const int lane = threadIdx.x & 63;
  const int wv = threadIdx.x >> 6;
  const int node_base = blockIdx.x * 64 + wv * 16;
  const int r16 = lane & 15;
  const int kg = lane >> 4;
  int arow = node_base + r16;
  if (arow >= N) arow = N - 1;

  f32x4 acc[8];
#pragma unroll
  for (int i = 0; i < 8; i++) acc[i] = (f32x4){0.f, 0.f, 0.f, 0.f};

  const ushort* a0 = aggb + (long)arow * 128 + kg * 8;
  const ushort* a1 = xb + (long)arow * 128 + kg * 8;
  const ushort* wb = w1t + r16 * 256 + kg * 8;

#pragma unroll
  for (int s = 0; s < 8; s++) {
    short8 a = (s < 4) ? *(const short8*)(a0 + s * 32)
                       : *(const short8*)(a1 + (s - 4) * 32);
#pragma unroll
    for (int ct = 0; ct < 8; ct++) {
      short8 b = *(const short8*)(wb + ct * (16 * 256) + s * 32);
      acc[ct] = __builtin_amdgcn_mfma_f32_16x16x32_bf16(a, b, acc[ct], 0, 0, 0);
    }
  }

#pragma unroll
  for (int ct = 0; ct < 8; ct++) {
    int j = ct * 16 + r16;
    float bb = b1[j];
#pragma unroll
    for (int r = 0; r < 4; r++) {
      int n = node_base + kg * 4 + r;
      if (n < N) {
        float h = fmaxf(acc[ct][r] + bb, 0.f);
        uint32_t fi = (uint32_t)n * 128u + (uint32_t)j;
        uint32_t t0 = 0u, t1 = fi;
        threefry2x32(0u, 42u, t0, t1);
        h1d[fi] = (((t0 ^ t1) >> 31) == 0u) ? f2bf(2.0f * h) : (ushort)0;
      }
    }
  }
}

// ---------------------------------------------------------------------------
// layer 2 (MFMA) + log_softmax: out = logsm([agg2|h1]@[W2l;W2r] + b2)
// wave computes 16 nodes x 64 cols; softmax over 16-lane groups x 4 regs
// ---------------------------------------------------------------------------
__global__ __launch_bounds__(256) void layer2_kernel(
    const ushort* __restrict__ aggb, const ushort* __restrict__ h1d,
    const ushort* __restrict__ w2t, const float* __restrict__ b2,
    float* __restrict__ out, int N) {
  const int lane = threadIdx.x & 63;
  const int wv = threadIdx.x >> 6;
  const int node_base = blockIdx.x * 64 + wv * 16;
  const int r16 = lane & 15;
  const int kg = lane >> 4;
  int arow = node_base + r16;
  if (arow >= N) arow = N - 1;

  f32x4 acc[4];
#pragma unroll
  for (int i = 0; i < 4; i++) acc[i] = (f32x4){0.f, 0.f, 0.f, 0.f};

  const ushort* a0 = aggb + (long)arow * 128 + kg * 8;
  const ushort* a1 = h1d + (long)arow * 128 + kg * 8;
  const ushort* wb = w2t + r16 * 256 + kg * 8;

#pragma unroll
  for (int s = 0; s < 8; s++) {
    short8 a = (s < 4) ? *(const short8*)(a0 + s * 32)
                       : *(const short8*)(a1 + (s - 4) * 32);
#pragma unroll
    for (int ct = 0; ct < 4; ct++) {
      short8 b = *(const short8*)(wb + ct * (16 * 256) + s * 32);
      acc[ct] = __builtin_amdgcn_mfma_f32_16x16x32_bf16(a, b, acc[ct], 0, 0, 0);
    }
  }

  float bb[4];
#pragma unroll
  for (int ct = 0; ct < 4; ct++) bb[ct] = b2[ct * 16 + r16];

#pragma unroll
  for (int r = 0; r < 4; r++) {
    float v[4];
#pragma unroll
    for (int ct = 0; ct < 4; ct++) v[ct] = acc[ct][r] + bb[ct];
    float m = fmaxf(fmaxf(v[0], v[1]), fmaxf(v[2], v[3]));
#pragma unroll
    for (int off = 1; off < 16; off <<= 1) m = fmaxf(m, __shfl_xor(m, off));
    float s = expf(v[0] - m) + expf(v[1] - m) + expf(v[2] - m) + expf(v[3] - m);
#pragma unroll
    for (int off = 1; off < 16; off <<= 1) s += __shfl_xor(s, off);
    float ls = logf(s);
    int n = node_base + kg * 4 + r;
    if (n < N) {
#pragma unroll
      for (int ct = 0; ct < 4; ct++)
        out[(long)n * 64 + ct * 16 + r16] = v[ct] - m - ls;
    }
  }
}

// ---------------------------------------------------------------------------
extern "C" void kernel_launch(void* const* d_in, const int* in_sizes, int n_in,
                              void* d_out, int out_size, void* d_ws, size_t ws_size,
                              hipStream_t stream) {
  const float* x   = (const float*)d_in[0];
  const void*  ei  = d_in[1];
  const float* W1l = (const float*)d_in[2];
  const float* b1  = (const float*)d_in[3];
  const float* W1r = (const float*)d_in[4];
  const float* W2l = (const float*)d_in[5];
  const float* b2  = (const float*)d_in[6];
  const float* W2r = (const float*)d_in[7];
  float* out = (float*)d_out;

  const int  N  = in_sizes[0] / D_FEAT;    // 100000
  const long E  = (long)in_sizes[1] / 2;   // 1600000
  const long NF = (long)N * D_FEAT;        // 12.8M

  char* ws = (char*)d_ws;
  size_t off = 0;
  auto alloc = [&](size_t bytes) -> void* {
    void* p = ws + off;
    off = (off + bytes + 255) & ~(size_t)255;
    return p;
  };
  int*    cnt    = (int*)alloc(sizeof(int) * N);
  int*    rowptr = (int*)alloc(sizeof(int) * (N + 1));
  int*    cur    = (int*)alloc(sizeof(int) * N);
  int*    bsum   = (int*)alloc(sizeof(int) * 256);
  int*    col    = (int*)alloc(sizeof(int) * E);
  float*  invd   = (float*)alloc(sizeof(float) * N);
  ushort* xb     = (ushort*)alloc(sizeof(ushort) * NF);
  ushort* aggb   = (ushort*)alloc(sizeof(ushort) * NF);  // reused for both layers
  ushort* h1d    = (ushort*)alloc(sizeof(ushort) * NF);
  ushort* w1t    = (ushort*)alloc(sizeof(ushort) * 128 * 256);
  ushort* w2t    = (ushort*)alloc(sizeof(ushort) * 64 * 256);
  int*    flag   = (int*)alloc(sizeof(int));

  const int NB = (N + 1023) / 1024;

  hipMemsetAsync(cnt, 0, sizeof(int) * N, stream);

  detect_kernel<<<1, 64, 0, stream>>>((const uint32_t*)ei, flag);
  convx_kernel<<<(int)((NF / 4 + 255) / 256), 256, 0, stream>>>((const float4*)x, xb, NF / 4);
  packw1_kernel<<<128, 256, 0, stream>>>(W1l, W1r, w1t);
  packw2_kernel<<<64, 256, 0, stream>>>(W2l, W2r, w2t);

  hist_kernel<<<(int)((E + 255) / 256), 256, 0, stream>>>(ei, flag, cnt, E);
  scanA_kernel<<<NB, 256, 0, stream>>>(cnt, rowptr, bsum, N);
  scanB_kernel<<<1, 128, 0, stream>>>(bsum, NB);
  scanC_kernel<<<(N + 256) / 256, 256, 0, stream>>>(rowptr, bsum, N, (int)E);
  hipMemcpyAsync(cur, rowptr, sizeof(int) * N, hipMemcpyDeviceToDevice, stream);
  fill_kernel<<<(int)((E + 255) / 256), 256, 0, stream>>>(ei, flag, cur, col, E);
  inv_kernel<<<(N + 255) / 256, 256, 0, stream>>>(rowptr, invd, N);

  const int aggBlocks = (int)(((long)N * 64 + 255) / 256);
  const int gemmBlocks = (N + 63) / 64;

  agg_kernel<<<aggBlocks, 256, 0, stream>>>(xb, rowptr, col, invd, aggb, N);
  layer1_kernel<<<gemmBlocks, 256, 0, stream>>>(aggb, xb, w1t, b1, h1d, N);

  agg_kernel<<<aggBlocks, 256, 0, stream>>>(h1d, rowptr, col, invd, aggb, N);
  layer2_kernel<<<gemmBlocks, 256, 0, stream>>>(aggb, h1d, w2t, b2, out, N);
}

// Round 4
// 385.067 us; speedup vs baseline: 8.0935x; 1.4005x over previous
//
#include <hip/hip_runtime.h>
#include <stdint.h>

#define D_FEAT 128
#define D_OUT  64
#define BSH 7              // 128 nodes per bucket
#define MAXB 1024          // max buckets (N <= 131072)

typedef __attribute__((ext_vector_type(8))) short short8;   // 8 bf16 (4 VGPRs)
typedef __attribute__((ext_vector_type(4))) float f32x4;

// ---------------------------------------------------------------------------
// helpers
// ---------------------------------------------------------------------------
__device__ __forceinline__ ushort f2bf(float f) {            // RNE f32->bf16
  uint32_t u = __float_as_uint(f);
  return (ushort)((u + 0x7FFFu + ((u >> 16) & 1u)) >> 16);
}
__device__ __forceinline__ float bfhi2f(uint32_t v) { return __uint_as_float(v & 0xFFFF0000u); }
__device__ __forceinline__ float bflo2f(uint32_t v) { return __uint_as_float(v << 16); }

__device__ __forceinline__ void threefry2x32(uint32_t k0, uint32_t k1,
                                             uint32_t& x0, uint32_t& x1) {
  uint32_t k2 = k0 ^ k1 ^ 0x1BD11BDAu;
#define TF_ROT(r) { x0 += x1; x1 = (x1 << (r)) | (x1 >> (32 - (r))); x1 ^= x0; }
  x0 += k0; x1 += k1;
  TF_ROT(13) TF_ROT(15) TF_ROT(26) TF_ROT(6)
  x0 += k1; x1 += k2 + 1u;
  TF_ROT(17) TF_ROT(29) TF_ROT(16) TF_ROT(24)
  x0 += k2; x1 += k0 + 2u;
  TF_ROT(13) TF_ROT(15) TF_ROT(26) TF_ROT(6)
  x0 += k0; x1 += k1 + 3u;
  TF_ROT(17) TF_ROT(29) TF_ROT(16) TF_ROT(24)
  x0 += k1; x1 += k2 + 4u;
  TF_ROT(13) TF_ROT(15) TF_ROT(26) TF_ROT(6)
  x0 += k2; x1 += k0 + 5u;
#undef TF_ROT
}

// ---------------------------------------------------------------------------
// edge_index dtype detection: int64 rows => all odd u32 words are zero
// ---------------------------------------------------------------------------
__global__ void detect_kernel(const uint32_t* __restrict__ ei, int* __restrict__ flag) {
  uint32_t v = ei[2 * threadIdx.x + 1];
  unsigned long long nz = __ballot(v != 0u);
  if (threadIdx.x == 0) flag[0] = (nz == 0ull) ? 1 : 0;
}

__device__ __forceinline__ int load_dst(const void* ei, int is64, long E, long e) {
  return is64 ? (int)((const long long*)ei)[E + e] : ((const int*)ei)[E + e];
}
__device__ __forceinline__ int load_src(const void* ei, int is64, long E, long e) {
  return is64 ? (int)((const long long*)ei)[e] : ((const int*)ei)[e];
}

// ---------------------------------------------------------------------------
// input conversions / weight packing
// ---------------------------------------------------------------------------
__global__ __launch_bounds__(256) void convx_kernel(
    const float4* __restrict__ x, ushort* __restrict__ xb, long n4) {
  long i = (long)blockIdx.x * blockDim.x + threadIdx.x;
  if (i >= n4) return;
  float4 v = x[i];
  ushort4 o = {f2bf(v.x), f2bf(v.y), f2bf(v.z), f2bf(v.w)};
  *(ushort4*)(xb + i * 4) = o;
}

// w1t[j][k] = bf16(k<128 ? W1l[k][j] : W1r[k-128][j]),  j<128, k<256
__global__ __launch_bounds__(256) void packw1_kernel(
    const float* __restrict__ Wl, const float* __restrict__ Wr,
    ushort* __restrict__ wt) {
  int idx = blockIdx.x * blockDim.x + threadIdx.x;   // 128*256
  if (idx >= 128 * 256) return;
  int j = idx >> 8, k = idx & 255;
  float v = (k < 128) ? Wl[k * 128 + j] : Wr[(k - 128) * 128 + j];
  wt[j * 256 + k] = f2bf(v);
}

// w2t[j][k] = bf16(k<128 ? W2l[k][j] : W2r[k-128][j]),  j<64, k<256
__global__ __launch_bounds__(256) void packw2_kernel(
    const float* __restrict__ Wl, const float* __restrict__ Wr,
    ushort* __restrict__ wt) {
  int idx = blockIdx.x * blockDim.x + threadIdx.x;   // 64*256
  if (idx >= 64 * 256) return;
  int j = idx >> 8, k = idx & 255;
  float v = (k < 128) ? Wl[k * 64 + j] : Wr[(k - 128) * 64 + j];
  wt[j * 256 + k] = f2bf(v);
}

// ---------------------------------------------------------------------------
// CSR build via bucketed counting sort (no random 4B scatter)
// ---------------------------------------------------------------------------
// S1: per-block LDS bucket histogram -> global bucketCnt
__global__ __launch_bounds__(256) void bucket_hist(
    const void* __restrict__ ei, const int* __restrict__ flag,
    int* __restrict__ bucketCnt, long E, int chunk, int nbuck) {
  __shared__ int cnt[MAXB];
  const int is64 = flag[0];
  long beg = (long)blockIdx.x * chunk;
  long end = beg + chunk; if (end > E) end = E;
  for (int i = threadIdx.x; i < nbuck; i += 256) cnt[i] = 0;
  __syncthreads();
  for (long e = beg + threadIdx.x; e < end; e += 256)
    atomicAdd(&cnt[load_dst(ei, is64, E, e) >> BSH], 1);
  __syncthreads();
  for (int i = threadIdx.x; i < nbuck; i += 256)
    if (cnt[i]) atomicAdd(&bucketCnt[i], cnt[i]);
}

// scan buckets (single block, 1024 threads); also seeds cursors & rowptr[N]
__global__ __launch_bounds__(1024) void bucket_scan(
    const int* __restrict__ bucketCnt, int* __restrict__ bucketPtr,
    int* __restrict__ bucketCur, int* __restrict__ rowptr,
    int N, int nbuck, int E) {
  __shared__ int ts[1024];
  int tid = threadIdx.x;
  int v = (tid < nbuck) ? bucketCnt[tid] : 0;
  ts[tid] = v;
  __syncthreads();
  for (int off = 1; off < 1024; off <<= 1) {
    int t = (tid >= off) ? ts[tid - off] : 0;
    __syncthreads();
    ts[tid] += t;
    __syncthreads();
  }
  if (tid < nbuck) {
    int excl = ts[tid] - v;
    bucketPtr[tid] = excl;
    bucketCur[tid] = excl;
  }
  if (tid == 0) { bucketPtr[nbuck] = E; rowptr[N] = E; }
}

// S2: scatter packed (src<<BSH | dst&mask) into bucket regions
__global__ __launch_bounds__(256) void bucket_scatter(
    const void* __restrict__ ei, const int* __restrict__ flag,
    int* __restrict__ bucketCur, uint32_t* __restrict__ packed,
    long E, int chunk, int nbuck) {
  __shared__ int cnt[MAXB];
  __shared__ int base[MAXB];
  __shared__ int cur[MAXB];
  const int is64 = flag[0];
  long beg = (long)blockIdx.x * chunk;
  long end = beg + chunk; if (end > E) end = E;
  for (int i = threadIdx.x; i < nbuck; i += 256) { cnt[i] = 0; cur[i] = 0; }
  __syncthreads();
  for (long e = beg + threadIdx.x; e < end; e += 256)
    atomicAdd(&cnt[load_dst(ei, is64, E, e) >> BSH], 1);
  __syncthreads();
  for (int i = threadIdx.x; i < nbuck; i += 256)
    base[i] = cnt[i] ? atomicAdd(&bucketCur[i], cnt[i]) : 0;
  __syncthreads();
  for (long e = beg + threadIdx.x; e < end; e += 256) {
    int dst = load_dst(ei, is64, E, e);
    int src = load_src(ei, is64, E, e);
    int b = dst >> BSH;
    int off = atomicAdd(&cur[b], 1);
    packed[base[b] + off] = ((uint32_t)src << BSH) | (uint32_t)(dst & ((1 << BSH) - 1));
  }
}

// S3: per bucket -> local hist + scan -> rowptr, invd, contiguous col writes
__global__ __launch_bounds__(256) void bucket_build(
    const uint32_t* __restrict__ packed, const int* __restrict__ bucketPtr,
    int* __restrict__ col, int* __restrict__ rowptr, float* __restrict__ invd,
    int N, int nbuck) {
  __shared__ int lcnt[1 << BSH];
  __shared__ int lbase[1 << BSH];
  __shared__ int lcur[1 << BSH];
  const int b = blockIdx.x;
  const int tid = threadIdx.x;
  const int beg = bucketPtr[b], end = bucketPtr[b + 1];
  if (tid < 128) { lcnt[tid] = 0; lcur[tid] = 0; }
  __syncthreads();
  for (int i = beg + tid; i < end; i += 256)
    atomicAdd(&lcnt[packed[i] & 127], 1);
  __syncthreads();
  if (tid < 128) lbase[tid] = lcnt[tid];
  __syncthreads();
  for (int off = 1; off < 128; off <<= 1) {
    int t = (tid >= off && tid < 128) ? lbase[tid - off] : 0;
    __syncthreads();
    if (tid < 128) lbase[tid] += t;
    __syncthreads();
  }
  if (tid < 128) {
    int excl = lbase[tid] - lcnt[tid];
    lbase[tid] = excl;
    int n = (b << BSH) + tid;
    if (n < N) {
      rowptr[n] = beg + excl;
      int d = lcnt[tid];
      invd[n] = 1.0f / (float)(d > 1 ? d : 1);
    }
  }
  __syncthreads();
  for (int i = beg + tid; i < end; i += 256) {
    uint32_t p = packed[i];
    int l = p & 127;
    int pos = beg + lbase[l] + atomicAdd(&lcur[l], 1);
    col[pos] = (int)(p >> BSH);
  }
}

// ---------------------------------------------------------------------------
// gather-style mean aggregation (bf16 in, fp32 accum, bf16 out)
// one wave per node, 2 bf16 (4 B) per lane
// ---------------------------------------------------------------------------
__global__ __launch_bounds__(256) void agg_kernel(
    const ushort* __restrict__ featb, const int* __restrict__ rowptr,
    const int* __restrict__ col, const float* __restrict__ invd,
    ushort* __restrict__ aggb, int N) {
  const int lane = threadIdx.x & 63;
  int n = (int)(((long)blockIdx.x * blockDim.x + threadIdx.x) >> 6);
  if (n >= N) return;
  int beg = rowptr[n], end = rowptr[n + 1];
  float ax = 0.f, ay = 0.f;
  int e = beg;
  for (; e + 1 < end; e += 2) {
    int s0 = col[e], s1 = col[e + 1];
    uint32_t v0 = *(const uint32_t*)(featb + (long)s0 * D_FEAT + lane * 2);
    uint32_t v1 = *(const uint32_t*)(featb + (long)s1 * D_FEAT + lane * 2);
    ax += bflo2f(v0) + bflo2f(v1);
    ay += bfhi2f(v0) + bfhi2f(v1);
  }
  if (e < end) {
    uint32_t v0 = *(const uint32_t*)(featb + (long)col[e] * D_FEAT + lane * 2);
    ax += bflo2f(v0);
    ay += bfhi2f(v0);
  }
  float sc = invd[n];
  uint32_t o = (uint32_t)f2bf(ax * sc) | ((uint32_t)f2bf(ay * sc) << 16);
  *(uint32_t*)(aggb + (long)n * D_FEAT + lane * 2) = o;
}

// ---------------------------------------------------------------------------
// layer 1 (MFMA): h1d = bf16(dropout(relu([agg|x]@[W1l;W1r] + b1)))
// block = 256 = 4 waves; wave computes 16 nodes x 128 cols
// ---------------------------------------------------------------------------
__global__ __launch_bounds__(256) void layer1_kernel(
    const ushort* __restrict__ aggb, const ushort* __restrict__ xb,
    const ushort* __restrict__ w1t, const float* __restrict__ b1,
    ushort* __restrict__ h1d, int N) {
  const int lane = threadIdx.x & 63;
  const int wv = threadIdx.x >> 6;
  const int node_base = blockIdx.x * 64 + wv * 16;
  const int r16 = lane & 15;
  const int kg = lane >> 4;
  int arow = node_base + r16;
  if (arow >= N) arow = N - 1;

  f32x4 acc[8];
#pragma unroll
  for (int i = 0; i < 8; i++) acc[i] = (f32x4){0.f, 0.f, 0.f, 0.f};

  const ushort* a0 = aggb + (long)arow * 128 + kg * 8;
  const ushort* a1 = xb + (long)arow * 128 + kg * 8;
  const ushort* wb = w1t + r16 * 256 + kg * 8;

#pragma unroll
  for (int s = 0; s < 8; s++) {
    short8 a = (s < 4) ? *(const short8*)(a0 + s * 32)
                       : *(const short8*)(a1 + (s - 4) * 32);
#pragma unroll
    for (int ct = 0; ct < 8; ct++) {
      short8 b = *(const short8*)(wb + ct * (16 * 256) + s * 32);
      acc[ct] = __builtin_amdgcn_mfma_f32_16x16x32_bf16(a, b, acc[ct], 0, 0, 0);
    }
  }

#pragma unroll
  for (int ct = 0; ct < 8; ct++) {
    int j = ct * 16 + r16;
    float bb = b1[j];
#pragma unroll
    for (int r = 0; r < 4; r++) {
      int n = node_base + kg * 4 + r;
      if (n < N) {
        float h = fmaxf(acc[ct][r] + bb, 0.f);
        uint32_t fi = (uint32_t)n * 128u + (uint32_t)j;
        uint32_t t0 = 0u, t1 = fi;
        threefry2x32(0u, 42u, t0, t1);
        h1d[fi] = (((t0 ^ t1) >> 31) == 0u) ? f2bf(2.0f * h) : (ushort)0;
      }
    }
  }
}

// ---------------------------------------------------------------------------
// layer 2 (MFMA) + log_softmax: out = logsm([agg2|h1]@[W2l;W2r] + b2)
// ---------------------------------------------------------------------------
__global__ __launch_bounds__(256) void layer2_kernel(
    const ushort* __restrict__ aggb, const ushort* __restrict__ h1d,
    const ushort* __restrict__ w2t, const float* __restrict__ b2,
    float* __restrict__ out, int N) {
  const int lane = threadIdx.x & 63;
  const int wv = threadIdx.x >> 6;
  const int node_base = blockIdx.x * 64 + wv * 16;
  const int r16 = lane & 15;
  const int kg = lane >> 4;
  int arow = node_base + r16;
  if (arow >= N) arow = N - 1;

  f32x4 acc[4];
#pragma unroll
  for (int i = 0; i < 4; i++) acc[i] = (f32x4){0.f, 0.f, 0.f, 0.f};

  const ushort* a0 = aggb + (long)arow * 128 + kg * 8;
  const ushort* a1 = h1d + (long)arow * 128 + kg * 8;
  const ushort* wb = w2t + r16 * 256 + kg * 8;

#pragma unroll
  for (int s = 0; s < 8; s++) {
    short8 a = (s < 4) ? *(const short8*)(a0 + s * 32)
                       : *(const short8*)(a1 + (s - 4) * 32);
#pragma unroll
    for (int ct = 0; ct < 4; ct++) {
      short8 b = *(const short8*)(wb + ct * (16 * 256) + s * 32);
      acc[ct] = __builtin_amdgcn_mfma_f32_16x16x32_bf16(a, b, acc[ct], 0, 0, 0);
    }
  }

  float bb[4];
#pragma unroll
  for (int ct = 0; ct < 4; ct++) bb[ct] = b2[ct * 16 + r16];

#pragma unroll
  for (int r = 0; r < 4; r++) {
    float v[4];
#pragma unroll
    for (int ct = 0; ct < 4; ct++) v[ct] = acc[ct][r] + bb[ct];
    float m = fmaxf(fmaxf(v[0], v[1]), fmaxf(v[2], v[3]));
#pragma unroll
    for (int off = 1; off < 16; off <<= 1) m = fmaxf(m, __shfl_xor(m, off));
    float s = expf(v[0] - m) + expf(v[1] - m) + expf(v[2] - m) + expf(v[3] - m);
#pragma unroll
    for (int off = 1; off < 16; off <<= 1) s += __shfl_xor(s, off);
    float ls = logf(s);
    int n = node_base + kg * 4 + r;
    if (n < N) {
#pragma unroll
      for (int ct = 0; ct < 4; ct++)
        out[(long)n * 64 + ct * 16 + r16] = v[ct] - m - ls;
    }
  }
}

// ---------------------------------------------------------------------------
extern "C" void kernel_launch(void* const* d_in, const int* in_sizes, int n_in,
                              void* d_out, int out_size, void* d_ws, size_t ws_size,
                              hipStream_t stream) {
  const float* x   = (const float*)d_in[0];
  const void*  ei  = d_in[1];
  const float* W1l = (const float*)d_in[2];
  const float* b1  = (const float*)d_in[3];
  const float* W1r = (const float*)d_in[4];
  const float* W2l = (const float*)d_in[5];
  const float* b2  = (const float*)d_in[6];
  const float* W2r = (const float*)d_in[7];
  float* out = (float*)d_out;

  const int  N  = in_sizes[0] / D_FEAT;    // 100000
  const long E  = (long)in_sizes[1] / 2;   // 1600000
  const long NF = (long)N * D_FEAT;        // 12.8M
  const int  nbuck = (N + (1 << BSH) - 1) >> BSH;   // 782

  char* ws = (char*)d_ws;
  size_t off = 0;
  auto alloc = [&](size_t bytes) -> void* {
    void* p = ws + off;
    off = (off + bytes + 255) & ~(size_t)255;
    return p;
  };
  int*      bucketCnt = (int*)alloc(sizeof(int) * MAXB);
  int*      bucketPtr = (int*)alloc(sizeof(int) * (MAXB + 1));
  int*      bucketCur = (int*)alloc(sizeof(int) * MAXB);
  int*      rowptr    = (int*)alloc(sizeof(int) * (N + 1));
  int*      col       = (int*)alloc(sizeof(int) * E);
  uint32_t* packed    = (uint32_t*)alloc(sizeof(uint32_t) * E);
  float*    invd      = (float*)alloc(sizeof(float) * N);
  ushort*   xb        = (ushort*)alloc(sizeof(ushort) * NF);
  ushort*   aggb      = (ushort*)alloc(sizeof(ushort) * NF);
  ushort*   h1d       = (ushort*)alloc(sizeof(ushort) * NF);
  ushort*   w1t       = (ushort*)alloc(sizeof(ushort) * 128 * 256);
  ushort*   w2t       = (ushort*)alloc(sizeof(ushort) * 64 * 256);
  int*      flag      = (int*)alloc(sizeof(int));

  const int chunkE = (int)((E + 255) / 256);   // edges per block, 256 blocks

  hipMemsetAsync(bucketCnt, 0, sizeof(int) * MAXB, stream);

  detect_kernel<<<1, 64, 0, stream>>>((const uint32_t*)ei, flag);
  convx_kernel<<<(int)((NF / 4 + 255) / 256), 256, 0, stream>>>((const float4*)x, xb, NF / 4);
  packw1_kernel<<<128, 256, 0, stream>>>(W1l, W1r, w1t);
  packw2_kernel<<<64, 256, 0, stream>>>(W2l, W2r, w2t);

  bucket_hist<<<256, 256, 0, stream>>>(ei, flag, bucketCnt, E, chunkE, nbuck);
  bucket_scan<<<1, 1024, 0, stream>>>(bucketCnt, bucketPtr, bucketCur, rowptr, N, nbuck, (int)E);
  bucket_scatter<<<256, 256, 0, stream>>>(ei, flag, bucketCur, packed, E, chunkE, nbuck);
  bucket_build<<<nbuck, 256, 0, stream>>>(packed, bucketPtr, col, rowptr, invd, N, nbuck);

  const int aggBlocks = (int)(((long)N * 64 + 255) / 256);
  const int gemmBlocks = (N + 63) / 64;

  agg_kernel<<<aggBlocks, 256, 0, stream>>>(xb, rowptr, col, invd, aggb, N);
  layer1_kernel<<<gemmBlocks, 256, 0, stream>>>(aggb, xb, w1t, b1, h1d, N);

  agg_kernel<<<aggBlocks, 256, 0, stream>>>(h1d, rowptr, col, invd, aggb, N);
  layer2_kernel<<<gemmBlocks, 256, 0, stream>>>(aggb, h1d, w2t, b2, out, N);
}

// Round 5
// 327.452 us; speedup vs baseline: 9.5175x; 1.1759x over previous
//
#include <hip/hip_runtime.h>
#include <stdint.h>

#define D_FEAT 128
#define D_OUT  64
#define BSH 7              // 128 nodes per bucket
#define MAXB 1024          // max buckets (N <= 131072)

typedef __attribute__((ext_vector_type(8))) short short8;   // 8 bf16 (4 VGPRs)
typedef __attribute__((ext_vector_type(8))) ushort ushort8; // 8 bf16
typedef __attribute__((ext_vector_type(4))) float f32x4;

// ---------------------------------------------------------------------------
// helpers
// ---------------------------------------------------------------------------
__device__ __forceinline__ ushort f2bf(float f) {            // RNE f32->bf16
  uint32_t u = __float_as_uint(f);
  return (ushort)((u + 0x7FFFu + ((u >> 16) & 1u)) >> 16);
}
__device__ __forceinline__ float bfhi2f(uint32_t v) { return __uint_as_float(v & 0xFFFF0000u); }
__device__ __forceinline__ float bflo2f(uint32_t v) { return __uint_as_float(v << 16); }

__device__ __forceinline__ void threefry2x32(uint32_t k0, uint32_t k1,
                                             uint32_t& x0, uint32_t& x1) {
  uint32_t k2 = k0 ^ k1 ^ 0x1BD11BDAu;
#define TF_ROT(r) { x0 += x1; x1 = (x1 << (r)) | (x1 >> (32 - (r))); x1 ^= x0; }
  x0 += k0; x1 += k1;
  TF_ROT(13) TF_ROT(15) TF_ROT(26) TF_ROT(6)
  x0 += k1; x1 += k2 + 1u;
  TF_ROT(17) TF_ROT(29) TF_ROT(16) TF_ROT(24)
  x0 += k2; x1 += k0 + 2u;
  TF_ROT(13) TF_ROT(15) TF_ROT(26) TF_ROT(6)
  x0 += k0; x1 += k1 + 3u;
  TF_ROT(17) TF_ROT(29) TF_ROT(16) TF_ROT(24)
  x0 += k1; x1 += k2 + 4u;
  TF_ROT(13) TF_ROT(15) TF_ROT(26) TF_ROT(6)
  x0 += k2; x1 += k0 + 5u;
#undef TF_ROT
}

// ---------------------------------------------------------------------------
// edge_index dtype detection: int64 rows => all odd u32 words are zero
// ---------------------------------------------------------------------------
__global__ void detect_kernel(const uint32_t* __restrict__ ei, int* __restrict__ flag) {
  uint32_t v = ei[2 * threadIdx.x + 1];
  unsigned long long nz = __ballot(v != 0u);
  if (threadIdx.x == 0) flag[0] = (nz == 0ull) ? 1 : 0;
}

__device__ __forceinline__ int load_dst(const void* ei, int is64, long E, long e) {
  return is64 ? (int)((const long long*)ei)[E + e] : ((const int*)ei)[E + e];
}
__device__ __forceinline__ int load_src(const void* ei, int is64, long E, long e) {
  return is64 ? (int)((const long long*)ei)[e] : ((const int*)ei)[e];
}

// ---------------------------------------------------------------------------
// input conversions / weight packing
// ---------------------------------------------------------------------------
__global__ __launch_bounds__(256) void convx_kernel(
    const float4* __restrict__ x, ushort* __restrict__ xb, long n4) {
  long i = (long)blockIdx.x * blockDim.x + threadIdx.x;
  if (i >= n4) return;
  float4 v = x[i];
  ushort4 o = {f2bf(v.x), f2bf(v.y), f2bf(v.z), f2bf(v.w)};
  *(ushort4*)(xb + i * 4) = o;
}

// w1t[j][k] = bf16(k<128 ? W1l[k][j] : W1r[k-128][j]),  j<128, k<256
__global__ __launch_bounds__(256) void packw1_kernel(
    const float* __restrict__ Wl, const float* __restrict__ Wr,
    ushort* __restrict__ wt) {
  int idx = blockIdx.x * blockDim.x + threadIdx.x;   // 128*256
  if (idx >= 128 * 256) return;
  int j = idx >> 8, k = idx & 255;
  float v = (k < 128) ? Wl[k * 128 + j] : Wr[(k - 128) * 128 + j];
  wt[j * 256 + k] = f2bf(v);
}

// w2t[j][k] = bf16(k<128 ? W2l[k][j] : W2r[k-128][j]),  j<64, k<256
__global__ __launch_bounds__(256) void packw2_kernel(
    const float* __restrict__ Wl, const float* __restrict__ Wr,
    ushort* __restrict__ wt) {
  int idx = blockIdx.x * blockDim.x + threadIdx.x;   // 64*256
  if (idx >= 64 * 256) return;
  int j = idx >> 8, k = idx & 255;
  float v = (k < 128) ? Wl[k * 64 + j] : Wr[(k - 128) * 64 + j];
  wt[j * 256 + k] = f2bf(v);
}

// ---------------------------------------------------------------------------
// CSR build via bucketed counting sort (no random 4B scatter)
// ---------------------------------------------------------------------------
__global__ __launch_bounds__(256) void bucket_hist(
    const void* __restrict__ ei, const int* __restrict__ flag,
    int* __restrict__ bucketCnt, long E, int chunk, int nbuck) {
  __shared__ int cnt[MAXB];
  const int is64 = flag[0];
  long beg = (long)blockIdx.x * chunk;
  long end = beg + chunk; if (end > E) end = E;
  for (int i = threadIdx.x; i < nbuck; i += 256) cnt[i] = 0;
  __syncthreads();
  for (long e = beg + threadIdx.x; e < end; e += 256)
    atomicAdd(&cnt[load_dst(ei, is64, E, e) >> BSH], 1);
  __syncthreads();
  for (int i = threadIdx.x; i < nbuck; i += 256)
    if (cnt[i]) atomicAdd(&bucketCnt[i], cnt[i]);
}

// scan buckets (single block, 1024 threads); also seeds cursors & rowptr[N]
__global__ __launch_bounds__(1024) void bucket_scan(
    const int* __restrict__ bucketCnt, int* __restrict__ bucketPtr,
    int* __restrict__ bucketCur, int* __restrict__ rowptr,
    int N, int nbuck, int E) {
  __shared__ int ts[1024];
  int tid = threadIdx.x;
  int v = (tid < nbuck) ? bucketCnt[tid] : 0;
  ts[tid] = v;
  __syncthreads();
  for (int off = 1; off < 1024; off <<= 1) {
    int t = (tid >= off) ? ts[tid - off] : 0;
    __syncthreads();
    ts[tid] += t;
    __syncthreads();
  }
  if (tid < nbuck) {
    int excl = ts[tid] - v;
    bucketPtr[tid] = excl;
    bucketCur[tid] = excl;
  }
  if (tid == 0) { bucketPtr[nbuck] = E; rowptr[N] = E; }
}

// S2: scatter packed (src<<BSH | dst&mask) into bucket regions
__global__ __launch_bounds__(256) void bucket_scatter(
    const void* __restrict__ ei, const int* __restrict__ flag,
    int* __restrict__ bucketCur, uint32_t* __restrict__ packed,
    long E, int chunk, int nbuck) {
  __shared__ int cnt[MAXB];
  __shared__ int base[MAXB];
  __shared__ int cur[MAXB];
  const int is64 = flag[0];
  long beg = (long)blockIdx.x * chunk;
  long end = beg + chunk; if (end > E) end = E;
  for (int i = threadIdx.x; i < nbuck; i += 256) { cnt[i] = 0; cur[i] = 0; }
  __syncthreads();
  for (long e = beg + threadIdx.x; e < end; e += 256)
    atomicAdd(&cnt[load_dst(ei, is64, E, e) >> BSH], 1);
  __syncthreads();
  for (int i = threadIdx.x; i < nbuck; i += 256)
    base[i] = cnt[i] ? atomicAdd(&bucketCur[i], cnt[i]) : 0;
  __syncthreads();
  for (long e = beg + threadIdx.x; e < end; e += 256) {
    int dst = load_dst(ei, is64, E, e);
    int src = load_src(ei, is64, E, e);
    int b = dst >> BSH;
    int off = atomicAdd(&cur[b], 1);
    packed[base[b] + off] = ((uint32_t)src << BSH) | (uint32_t)(dst & ((1 << BSH) - 1));
  }
}

// S3: per bucket -> local hist + scan -> rowptr, invd, contiguous col writes
__global__ __launch_bounds__(256) void bucket_build(
    const uint32_t* __restrict__ packed, const int* __restrict__ bucketPtr,
    int* __restrict__ col, int* __restrict__ rowptr, float* __restrict__ invd,
    int N, int nbuck) {
  __shared__ int lcnt[1 << BSH];
  __shared__ int lbase[1 << BSH];
  __shared__ int lcur[1 << BSH];
  const int b = blockIdx.x;
  const int tid = threadIdx.x;
  const int beg = bucketPtr[b], end = bucketPtr[b + 1];
  if (tid < 128) { lcnt[tid] = 0; lcur[tid] = 0; }
  __syncthreads();
  for (int i = beg + tid; i < end; i += 256)
    atomicAdd(&lcnt[packed[i] & 127], 1);
  __syncthreads();
  if (tid < 128) lbase[tid] = lcnt[tid];
  __syncthreads();
  for (int off = 1; off < 128; off <<= 1) {
    int t = (tid >= off && tid < 128) ? lbase[tid - off] : 0;
    __syncthreads();
    if (tid < 128) lbase[tid] += t;
    __syncthreads();
  }
  if (tid < 128) {
    int excl = lbase[tid] - lcnt[tid];
    lbase[tid] = excl;
    int n = (b << BSH) + tid;
    if (n < N) {
      rowptr[n] = beg + excl;
      int d = lcnt[tid];
      invd[n] = 1.0f / (float)(d > 1 ? d : 1);
    }
  }
  __syncthreads();
  for (int i = beg + tid; i < end; i += 256) {
    uint32_t p = packed[i];
    int l = p & 127;
    int pos = beg + lbase[l] + atomicAdd(&lcur[l], 1);
    col[pos] = (int)(p >> BSH);
  }
}

// ---------------------------------------------------------------------------
// gather-style mean aggregation (bf16 in, fp32 accum, bf16 out)
// one wave per node; 16 B/lane -> quarter-wave per source row, 4 edges/iter
// ---------------------------------------------------------------------------
__global__ __launch_bounds__(256) void agg_kernel(
    const ushort* __restrict__ featb, const int* __restrict__ rowptr,
    const int* __restrict__ col, const float* __restrict__ invd,
    ushort* __restrict__ aggb, int N) {
  const int lane = threadIdx.x & 63;
  const int q  = lane >> 4;    // quarter 0..3: which edge of the group of 4
  const int sl = lane & 15;    // sublane: 16 B slice of the 256 B row
  int n = (int)(((long)blockIdx.x * blockDim.x + threadIdx.x) >> 6);
  if (n >= N) return;
  int beg = rowptr[n], end = rowptr[n + 1];

  float acc[8];
#pragma unroll
  for (int i = 0; i < 8; i++) acc[i] = 0.f;

  for (int e = beg; e < end; e += 4) {
    int idx = e + q;
    bool valid = idx < end;
    int s = col[valid ? idx : beg];          // clamped: beg always valid here
    uint4 v = *(const uint4*)(featb + (long)s * D_FEAT + sl * 8);
    if (valid) {
      acc[0] += bflo2f(v.x); acc[1] += bfhi2f(v.x);
      acc[2] += bflo2f(v.y); acc[3] += bfhi2f(v.y);
      acc[4] += bflo2f(v.z); acc[5] += bfhi2f(v.z);
      acc[6] += bflo2f(v.w); acc[7] += bfhi2f(v.w);
    }
  }

  // combine the 4 quarter-wave partial sums (lanes with equal sl)
#pragma unroll
  for (int i = 0; i < 8; i++) {
    acc[i] += __shfl_xor(acc[i], 16);
    acc[i] += __shfl_xor(acc[i], 32);
  }

  if (q == 0) {
    float sc = invd[n];
    ushort8 o;
#pragma unroll
    for (int i = 0; i < 8; i++) o[i] = f2bf(acc[i] * sc);
    *(ushort8*)(aggb + (long)n * D_FEAT + sl * 8) = o;
  }
}

// ---------------------------------------------------------------------------
// layer 1 (MFMA): h1d = bf16(dropout(relu([agg|x]@[W1l;W1r] + b1)))
// block = 256 = 4 waves; wave computes 16 nodes x 128 cols
// ---------------------------------------------------------------------------
__global__ __launch_bounds__(256) void layer1_kernel(
    const ushort* __restrict__ aggb, const ushort* __restrict__ xb,
    const ushort* __restrict__ w1t, const float* __restrict__ b1,
    ushort* __restrict__ h1d, int N) {
  const int lane = threadIdx.x & 63;
  const int wv = threadIdx.x >> 6;
  const int node_base = blockIdx.x * 64 + wv * 16;
  const int r16 = lane & 15;
  const int kg = lane >> 4;
  int arow = node_base + r16;
  if (arow >= N) arow = N - 1;

  f32x4 acc[8];
#pragma unroll
  for (int i = 0; i < 8; i++) acc[i] = (f32x4){0.f, 0.f, 0.f, 0.f};

  const ushort* a0 = aggb + (long)arow * 128 + kg * 8;
  const ushort* a1 = xb + (long)arow * 128 + kg * 8;
  const ushort* wb = w1t + r16 * 256 + kg * 8;

#pragma unroll
  for (int s = 0; s < 8; s++) {
    short8 a = (s < 4) ? *(const short8*)(a0 + s * 32)
                       : *(const short8*)(a1 + (s - 4) * 32);
#pragma unroll
    for (int ct = 0; ct < 8; ct++) {
      short8 b = *(const short8*)(wb + ct * (16 * 256) + s * 32);
      acc[ct] = __builtin_amdgcn_mfma_f32_16x16x32_bf16(a, b, acc[ct], 0, 0, 0);
    }
  }

#pragma unroll
  for (int ct = 0; ct < 8; ct++) {
    int j = ct * 16 + r16;
    float bb = b1[j];
#pragma unroll
    for (int r = 0; r < 4; r++) {
      int n = node_base + kg * 4 + r;
      if (n < N) {
        float h = fmaxf(acc[ct][r] + bb, 0.f);
        uint32_t fi = (uint32_t)n * 128u + (uint32_t)j;
        uint32_t t0 = 0u, t1 = fi;
        threefry2x32(0u, 42u, t0, t1);
        h1d[fi] = (((t0 ^ t1) >> 31) == 0u) ? f2bf(2.0f * h) : (ushort)0;
      }
    }
  }
}

// ---------------------------------------------------------------------------
// layer 2 (MFMA) + log_softmax: out = logsm([agg2|h1]@[W2l;W2r] + b2)
// ---------------------------------------------------------------------------
__global__ __launch_bounds__(256) void layer2_kernel(
    const ushort* __restrict__ aggb, const ushort* __restrict__ h1d,
    const ushort* __restrict__ w2t, const float* __restrict__ b2,
    float* __restrict__ out, int N) {
  const int lane = threadIdx.x & 63;
  const int wv = threadIdx.x >> 6;
  const int node_base = blockIdx.x * 64 + wv * 16;
  const int r16 = lane & 15;
  const int kg = lane >> 4;
  int arow = node_base + r16;
  if (arow >= N) arow = N - 1;

  f32x4 acc[4];
#pragma unroll
  for (int i = 0; i < 4; i++) acc[i] = (f32x4){0.f, 0.f, 0.f, 0.f};

  const ushort* a0 = aggb + (long)arow * 128 + kg * 8;
  const ushort* a1 = h1d + (long)arow * 128 + kg * 8;
  const ushort* wb = w2t + r16 * 256 + kg * 8;

#pragma unroll
  for (int s = 0; s < 8; s++) {
    short8 a = (s < 4) ? *(const short8*)(a0 + s * 32)
                       : *(const short8*)(a1 + (s - 4) * 32);
#pragma unroll
    for (int ct = 0; ct < 4; ct++) {
      short8 b = *(const short8*)(wb + ct * (16 * 256) + s * 32);
      acc[ct] = __builtin_amdgcn_mfma_f32_16x16x32_bf16(a, b, acc[ct], 0, 0, 0);
    }
  }

  float bb[4];
#pragma unroll
  for (int ct = 0; ct < 4; ct++) bb[ct] = b2[ct * 16 + r16];

#pragma unroll
  for (int r = 0; r < 4; r++) {
    float v[4];
#pragma unroll
    for (int ct = 0; ct < 4; ct++) v[ct] = acc[ct][r] + bb[ct];
    float m = fmaxf(fmaxf(v[0], v[1]), fmaxf(v[2], v[3]));
#pragma unroll
    for (int off = 1; off < 16; off <<= 1) m = fmaxf(m, __shfl_xor(m, off));
    float s = expf(v[0] - m) + expf(v[1] - m) + expf(v[2] - m) + expf(v[3] - m);
#pragma unroll
    for (int off = 1; off < 16; off <<= 1) s += __shfl_xor(s, off);
    float ls = logf(s);
    int n = node_base + kg * 4 + r;
    if (n < N) {
#pragma unroll
      for (int ct = 0; ct < 4; ct++)
        out[(long)n * 64 + ct * 16 + r16] = v[ct] - m - ls;
    }
  }
}

// ---------------------------------------------------------------------------
extern "C" void kernel_launch(void* const* d_in, const int* in_sizes, int n_in,
                              void* d_out, int out_size, void* d_ws, size_t ws_size,
                              hipStream_t stream) {
  const float* x   = (const float*)d_in[0];
  const void*  ei  = d_in[1];
  const float* W1l = (const float*)d_in[2];
  const float* b1  = (const float*)d_in[3];
  const float* W1r = (const float*)d_in[4];
  const float* W2l = (const float*)d_in[5];
  const float* b2  = (const float*)d_in[6];
  const float* W2r = (const float*)d_in[7];
  float* out = (float*)d_out;

  const int  N  = in_sizes[0] / D_FEAT;    // 100000
  const long E  = (long)in_sizes[1] / 2;   // 1600000
  const long NF = (long)N * D_FEAT;        // 12.8M
  const int  nbuck = (N + (1 << BSH) - 1) >> BSH;   // 782

  char* ws = (char*)d_ws;
  size_t off = 0;
  auto alloc = [&](size_t bytes) -> void* {
    void* p = ws + off;
    off = (off + bytes + 255) & ~(size_t)255;
    return p;
  };
  int*      bucketCnt = (int*)alloc(sizeof(int) * MAXB);
  int*      bucketPtr = (int*)alloc(sizeof(int) * (MAXB + 1));
  int*      bucketCur = (int*)alloc(sizeof(int) * MAXB);
  int*      rowptr    = (int*)alloc(sizeof(int) * (N + 1));
  int*      col       = (int*)alloc(sizeof(int) * E);
  uint32_t* packed    = (uint32_t*)alloc(sizeof(uint32_t) * E);
  float*    invd      = (float*)alloc(sizeof(float) * N);
  ushort*   xb        = (ushort*)alloc(sizeof(ushort) * NF);
  ushort*   aggb      = (ushort*)alloc(sizeof(ushort) * NF);
  ushort*   h1d       = (ushort*)alloc(sizeof(ushort) * NF);
  ushort*   w1t       = (ushort*)alloc(sizeof(ushort) * 128 * 256);
  ushort*   w2t       = (ushort*)alloc(sizeof(ushort) * 64 * 256);
  int*      flag      = (int*)alloc(sizeof(int));

  const int chunkE = (int)((E + 255) / 256);   // edges per block, 256 blocks

  hipMemsetAsync(bucketCnt, 0, sizeof(int) * MAXB, stream);

  detect_kernel<<<1, 64, 0, stream>>>((const uint32_t*)ei, flag);
  convx_kernel<<<(int)((NF / 4 + 255) / 256), 256, 0, stream>>>((const float4*)x, xb, NF / 4);
  packw1_kernel<<<128, 256, 0, stream>>>(W1l, W1r, w1t);
  packw2_kernel<<<64, 256, 0, stream>>>(W2l, W2r, w2t);

  bucket_hist<<<256, 256, 0, stream>>>(ei, flag, bucketCnt, E, chunkE, nbuck);
  bucket_scan<<<1, 1024, 0, stream>>>(bucketCnt, bucketPtr, bucketCur, rowptr, N, nbuck, (int)E);
  bucket_scatter<<<256, 256, 0, stream>>>(ei, flag, bucketCur, packed, E, chunkE, nbuck);
  bucket_build<<<nbuck, 256, 0, stream>>>(packed, bucketPtr, col, rowptr, invd, N, nbuck);

  const int aggBlocks = (int)(((long)N * 64 + 255) / 256);
  const int gemmBlocks = (N + 63) / 64;

  agg_kernel<<<aggBlocks, 256, 0, stream>>>(xb, rowptr, col, invd, aggb, N);
  layer1_kernel<<<gemmBlocks, 256, 0, stream>>>(aggb, xb, w1t, b1, h1d, N);

  agg_kernel<<<aggBlocks, 256, 0, stream>>>(h1d, rowptr, col, invd, aggb, N);
  layer2_kernel<<<gemmBlocks, 256, 0, stream>>>(aggb, h1d, w2t, b2, out, N);
}

// Round 6
// 308.528 us; speedup vs baseline: 10.1013x; 1.0613x over previous
//
#include <hip/hip_runtime.h>
#include <stdint.h>

#define D_FEAT 128
#define D_OUT  64
#define BSH 7              // 128 nodes per bucket
#define MAXB 1024          // max buckets (N <= 131072)

typedef __attribute__((ext_vector_type(8))) short short8;   // 8 bf16 (4 VGPRs)
typedef __attribute__((ext_vector_type(8))) ushort ushort8; // 8 bf16
typedef __attribute__((ext_vector_type(4))) float f32x4;

// ---------------------------------------------------------------------------
// helpers
// ---------------------------------------------------------------------------
__device__ __forceinline__ ushort f2bf(float f) {            // RNE f32->bf16
  uint32_t u = __float_as_uint(f);
  return (ushort)((u + 0x7FFFu + ((u >> 16) & 1u)) >> 16);
}
__device__ __forceinline__ float bfhi2f(uint32_t v) { return __uint_as_float(v & 0xFFFF0000u); }
__device__ __forceinline__ float bflo2f(uint32_t v) { return __uint_as_float(v << 16); }

__device__ __forceinline__ void threefry2x32(uint32_t k0, uint32_t k1,
                                             uint32_t& x0, uint32_t& x1) {
  uint32_t k2 = k0 ^ k1 ^ 0x1BD11BDAu;
#define TF_ROT(r) { x0 += x1; x1 = (x1 << (r)) | (x1 >> (32 - (r))); x1 ^= x0; }
  x0 += k0; x1 += k1;
  TF_ROT(13) TF_ROT(15) TF_ROT(26) TF_ROT(6)
  x0 += k1; x1 += k2 + 1u;
  TF_ROT(17) TF_ROT(29) TF_ROT(16) TF_ROT(24)
  x0 += k2; x1 += k0 + 2u;
  TF_ROT(13) TF_ROT(15) TF_ROT(26) TF_ROT(6)
  x0 += k0; x1 += k1 + 3u;
  TF_ROT(17) TF_ROT(29) TF_ROT(16) TF_ROT(24)
  x0 += k1; x1 += k2 + 4u;
  TF_ROT(13) TF_ROT(15) TF_ROT(26) TF_ROT(6)
  x0 += k2; x1 += k0 + 5u;
#undef TF_ROT
}

// keep iff top bit of (r0^r1) of threefry2x32((0,42), (0, i)) is 0
__device__ __forceinline__ bool keep_bit(uint32_t i) {
  uint32_t t0 = 0u, t1 = i;
  threefry2x32(0u, 42u, t0, t1);
  return (((t0 ^ t1) >> 31) == 0u);
}

// ---------------------------------------------------------------------------
// edge_index dtype detection: int64 rows => all odd u32 words are zero
// ---------------------------------------------------------------------------
__global__ void detect_kernel(const uint32_t* __restrict__ ei, int* __restrict__ flag) {
  uint32_t v = ei[2 * threadIdx.x + 1];
  unsigned long long nz = __ballot(v != 0u);
  if (threadIdx.x == 0) flag[0] = (nz == 0ull) ? 1 : 0;
}

__device__ __forceinline__ int load_dst(const void* ei, int is64, long E, long e) {
  return is64 ? (int)((const long long*)ei)[E + e] : ((const int*)ei)[E + e];
}
__device__ __forceinline__ int load_src(const void* ei, int is64, long E, long e) {
  return is64 ? (int)((const long long*)ei)[e] : ((const int*)ei)[e];
}

// ---------------------------------------------------------------------------
// input conversions / weight packing
// ---------------------------------------------------------------------------
__global__ __launch_bounds__(256) void convx_kernel(
    const float4* __restrict__ x, ushort* __restrict__ xb, long n4) {
  long i = (long)blockIdx.x * blockDim.x + threadIdx.x;
  if (i >= n4) return;
  float4 v = x[i];
  ushort4 o = {f2bf(v.x), f2bf(v.y), f2bf(v.z), f2bf(v.w)};
  *(ushort4*)(xb + i * 4) = o;
}

// w1t[j][k] = bf16(k<128 ? W1l[k][j] : W1r[k-128][j]),  j<128, k<256
__global__ __launch_bounds__(256) void packw1_kernel(
    const float* __restrict__ Wl, const float* __restrict__ Wr,
    ushort* __restrict__ wt) {
  int idx = blockIdx.x * blockDim.x + threadIdx.x;   // 128*256
  if (idx >= 128 * 256) return;
  int j = idx >> 8, k = idx & 255;
  float v = (k < 128) ? Wl[k * 128 + j] : Wr[(k - 128) * 128 + j];
  wt[j * 256 + k] = f2bf(v);
}

// w2t[j][k] = bf16(k<128 ? W2l[k][j] : W2r[k-128][j]),  j<64, k<256
__global__ __launch_bounds__(256) void packw2_kernel(
    const float* __restrict__ Wl, const float* __restrict__ Wr,
    ushort* __restrict__ wt) {
  int idx = blockIdx.x * blockDim.x + threadIdx.x;   // 64*256
  if (idx >= 64 * 256) return;
  int j = idx >> 8, k = idx & 255;
  float v = (k < 128) ? Wl[k * 64 + j] : Wr[(k - 128) * 64 + j];
  wt[j * 256 + k] = f2bf(v);
}

// ---------------------------------------------------------------------------
// CSR build via bucketed counting sort (no random 4B scatter)
// ---------------------------------------------------------------------------
__global__ __launch_bounds__(256) void bucket_hist(
    const void* __restrict__ ei, const int* __restrict__ flag,
    int* __restrict__ bucketCnt, long E, int chunk, int nbuck) {
  __shared__ int cnt[MAXB];
  const int is64 = flag[0];
  long beg = (long)blockIdx.x * chunk;
  long end = beg + chunk; if (end > E) end = E;
  for (int i = threadIdx.x; i < nbuck; i += 256) cnt[i] = 0;
  __syncthreads();
  for (long e = beg + threadIdx.x; e < end; e += 256)
    atomicAdd(&cnt[load_dst(ei, is64, E, e) >> BSH], 1);
  __syncthreads();
  for (int i = threadIdx.x; i < nbuck; i += 256)
    if (cnt[i]) atomicAdd(&bucketCnt[i], cnt[i]);
}

// scan buckets (single block, 1024 threads); also seeds cursors & rowptr[N]
__global__ __launch_bounds__(1024) void bucket_scan(
    const int* __restrict__ bucketCnt, int* __restrict__ bucketPtr,
    int* __restrict__ bucketCur, int* __restrict__ rowptr,
    int N, int nbuck, int E) {
  __shared__ int ts[1024];
  int tid = threadIdx.x;
  int v = (tid < nbuck) ? bucketCnt[tid] : 0;
  ts[tid] = v;
  __syncthreads();
  for (int off = 1; off < 1024; off <<= 1) {
    int t = (tid >= off) ? ts[tid - off] : 0;
    __syncthreads();
    ts[tid] += t;
    __syncthreads();
  }
  if (tid < nbuck) {
    int excl = ts[tid] - v;
    bucketPtr[tid] = excl;
    bucketCur[tid] = excl;
  }
  if (tid == 0) { bucketPtr[nbuck] = E; rowptr[N] = E; }
}

// S2: scatter packed (src<<BSH | dst&mask) into bucket regions
__global__ __launch_bounds__(256) void bucket_scatter(
    const void* __restrict__ ei, const int* __restrict__ flag,
    int* __restrict__ bucketCur, uint32_t* __restrict__ packed,
    long E, int chunk, int nbuck) {
  __shared__ int cnt[MAXB];
  __shared__ int base[MAXB];
  __shared__ int cur[MAXB];
  const int is64 = flag[0];
  long beg = (long)blockIdx.x * chunk;
  long end = beg + chunk; if (end > E) end = E;
  for (int i = threadIdx.x; i < nbuck; i += 256) { cnt[i] = 0; cur[i] = 0; }
  __syncthreads();
  for (long e = beg + threadIdx.x; e < end; e += 256)
    atomicAdd(&cnt[load_dst(ei, is64, E, e) >> BSH], 1);
  __syncthreads();
  for (int i = threadIdx.x; i < nbuck; i += 256)
    base[i] = cnt[i] ? atomicAdd(&bucketCur[i], cnt[i]) : 0;
  __syncthreads();
  for (long e = beg + threadIdx.x; e < end; e += 256) {
    int dst = load_dst(ei, is64, E, e);
    int src = load_src(ei, is64, E, e);
    int b = dst >> BSH;
    int off = atomicAdd(&cur[b], 1);
    packed[base[b] + off] = ((uint32_t)src << BSH) | (uint32_t)(dst & ((1 << BSH) - 1));
  }
}

// S3: per bucket -> local hist + scan -> rowptr, invd, contiguous col writes
__global__ __launch_bounds__(256) void bucket_build(
    const uint32_t* __restrict__ packed, const int* __restrict__ bucketPtr,
    int* __restrict__ col, int* __restrict__ rowptr, float* __restrict__ invd,
    int N, int nbuck) {
  __shared__ int lcnt[1 << BSH];
  __shared__ int lbase[1 << BSH];
  __shared__ int lcur[1 << BSH];
  const int b = blockIdx.x;
  const int tid = threadIdx.x;
  const int beg = bucketPtr[b], end = bucketPtr[b + 1];
  if (tid < 128) { lcnt[tid] = 0; lcur[tid] = 0; }
  __syncthreads();
  for (int i = beg + tid; i < end; i += 256)
    atomicAdd(&lcnt[packed[i] & 127], 1);
  __syncthreads();
  if (tid < 128) lbase[tid] = lcnt[tid];
  __syncthreads();
  for (int off = 1; off < 128; off <<= 1) {
    int t = (tid >= off && tid < 128) ? lbase[tid - off] : 0;
    __syncthreads();
    if (tid < 128) lbase[tid] += t;
    __syncthreads();
  }
  if (tid < 128) {
    int excl = lbase[tid] - lcnt[tid];
    lbase[tid] = excl;
    int n = (b << BSH) + tid;
    if (n < N) {
      rowptr[n] = beg + excl;
      int d = lcnt[tid];
      invd[n] = 1.0f / (float)(d > 1 ? d : 1);
    }
  }
  __syncthreads();
  for (int i = beg + tid; i < end; i += 256) {
    uint32_t p = packed[i];
    int l = p & 127;
    int pos = beg + lbase[l] + atomicAdd(&lcur[l], 1);
    col[pos] = (int)(p >> BSH);
  }
}

// ---------------------------------------------------------------------------
// gather-style mean aggregation (bf16 in, fp32 accum, bf16 out)
// one wave per node; 16 B/lane -> quarter-wave per source row, 8 edges/iter
// optionally generates the packed dropout mask (2 threefry + 2 ballots/wave)
// ---------------------------------------------------------------------------
__global__ __launch_bounds__(256) void agg_kernel(
    const ushort* __restrict__ featb, const int* __restrict__ rowptr,
    const int* __restrict__ col, const float* __restrict__ invd,
    ushort* __restrict__ aggb, unsigned long long* __restrict__ maskb, int N) {
  const int lane = threadIdx.x & 63;
  const int q  = lane >> 4;    // quarter 0..3
  const int sl = lane & 15;    // 16 B slice of the 256 B row
  int n = (int)(((long)blockIdx.x * blockDim.x + threadIdx.x) >> 6);
  if (n >= N) return;

  if (maskb) {  // dropout mask for node n, packed 128 bits -> 2 x u64
    uint32_t base = (uint32_t)n * 128u;
    bool k0 = keep_bit(base + (uint32_t)lane);
    bool k1 = keep_bit(base + 64u + (uint32_t)lane);
    unsigned long long w0 = __ballot(k0);
    unsigned long long w1 = __ballot(k1);
    if (lane == 0) {
      maskb[2 * n]     = w0;
      maskb[2 * n + 1] = w1;
    }
  }

  int beg = rowptr[n], end = rowptr[n + 1];

  float acc[8];
#pragma unroll
  for (int i = 0; i < 8; i++) acc[i] = 0.f;

  for (int e = beg; e < end; e += 8) {
    int i0 = e + q, i1 = e + 4 + q;
    bool v0 = i0 < end, v1 = i1 < end;
    int s0 = col[v0 ? i0 : beg];
    int s1 = col[v1 ? i1 : beg];
    uint4 a = *(const uint4*)(featb + (long)s0 * D_FEAT + sl * 8);
    uint4 b = *(const uint4*)(featb + (long)s1 * D_FEAT + sl * 8);
    if (v0) {
      acc[0] += bflo2f(a.x); acc[1] += bfhi2f(a.x);
      acc[2] += bflo2f(a.y); acc[3] += bfhi2f(a.y);
      acc[4] += bflo2f(a.z); acc[5] += bfhi2f(a.z);
      acc[6] += bflo2f(a.w); acc[7] += bfhi2f(a.w);
    }
    if (v1) {
      acc[0] += bflo2f(b.x); acc[1] += bfhi2f(b.x);
      acc[2] += bflo2f(b.y); acc[3] += bfhi2f(b.y);
      acc[4] += bflo2f(b.z); acc[5] += bfhi2f(b.z);
      acc[6] += bflo2f(b.w); acc[7] += bfhi2f(b.w);
    }
  }

  // combine the 4 quarter-wave partial sums (lanes with equal sl)
#pragma unroll
  for (int i = 0; i < 8; i++) {
    acc[i] += __shfl_xor(acc[i], 16);
    acc[i] += __shfl_xor(acc[i], 32);
  }

  if (q == 0) {
    float sc = invd[n];
    ushort8 o;
#pragma unroll
    for (int i = 0; i < 8; i++) o[i] = f2bf(acc[i] * sc);
    *(ushort8*)(aggb + (long)n * D_FEAT + sl * 8) = o;
  }
}

// ---------------------------------------------------------------------------
// layer 1 (MFMA): h1d = bf16(dropout(relu([agg|x]@[W1l;W1r] + b1)))
// block = 256 = 4 waves; wave computes 16 nodes x 128 cols
// dropout mask read from packed bits (no threefry here)
// ---------------------------------------------------------------------------
__global__ __launch_bounds__(256) void layer1_kernel(
    const ushort* __restrict__ aggb, const ushort* __restrict__ xb,
    const ushort* __restrict__ w1t, const float* __restrict__ b1,
    const unsigned long long* __restrict__ maskb,
    ushort* __restrict__ h1d, int N) {
  const int lane = threadIdx.x & 63;
  const int wv = threadIdx.x >> 6;
  const int node_base = blockIdx.x * 64 + wv * 16;
  const int r16 = lane & 15;
  const int kg = lane >> 4;
  int arow = node_base + r16;
  if (arow >= N) arow = N - 1;

  f32x4 acc[8];
#pragma unroll
  for (int i = 0; i < 8; i++) acc[i] = (f32x4){0.f, 0.f, 0.f, 0.f};

  const ushort* a0 = aggb + (long)arow * 128 + kg * 8;
  const ushort* a1 = xb + (long)arow * 128 + kg * 8;
  const ushort* wb = w1t + r16 * 256 + kg * 8;

#pragma unroll
  for (int s = 0; s < 8; s++) {
    short8 a = (s < 4) ? *(const short8*)(a0 + s * 32)
                       : *(const short8*)(a1 + (s - 4) * 32);
#pragma unroll
    for (int ct = 0; ct < 8; ct++) {
      short8 b = *(const short8*)(wb + ct * (16 * 256) + s * 32);
      acc[ct] = __builtin_amdgcn_mfma_f32_16x16x32_bf16(a, b, acc[ct], 0, 0, 0);
    }
  }

  float bbv[8];
#pragma unroll
  for (int ct = 0; ct < 8; ct++) bbv[ct] = b1[ct * 16 + r16];

#pragma unroll
  for (int r = 0; r < 4; r++) {
    int n = node_base + kg * 4 + r;
    if (n < N) {
      unsigned long long m0 = maskb[2 * n];
      unsigned long long m1 = maskb[2 * n + 1];
#pragma unroll
      for (int ct = 0; ct < 8; ct++) {
        int j = ct * 16 + r16;
        float h = fmaxf(acc[ct][r] + bbv[ct], 0.f);
        unsigned long long w = (j & 64) ? m1 : m0;
        bool keep = (w >> (j & 63)) & 1ull;
        h1d[(long)n * 128 + j] = keep ? f2bf(2.0f * h) : (ushort)0;
      }
    }
  }
}

// ---------------------------------------------------------------------------
// layer 2 (MFMA) + log_softmax: out = logsm([agg2|h1]@[W2l;W2r] + b2)
// ---------------------------------------------------------------------------
__global__ __launch_bounds__(256) void layer2_kernel(
    const ushort* __restrict__ aggb, const ushort* __restrict__ h1d,
    const ushort* __restrict__ w2t, const float* __restrict__ b2,
    float* __restrict__ out, int N) {
  const int lane = threadIdx.x & 63;
  const int wv = threadIdx.x >> 6;
  const int node_base = blockIdx.x * 64 + wv * 16;
  const int r16 = lane & 15;
  const int kg = lane >> 4;
  int arow = node_base + r16;
  if (arow >= N) arow = N - 1;

  f32x4 acc[4];
#pragma unroll
  for (int i = 0; i < 4; i++) acc[i] = (f32x4){0.f, 0.f, 0.f, 0.f};

  const ushort* a0 = aggb + (long)arow * 128 + kg * 8;
  const ushort* a1 = h1d + (long)arow * 128 + kg * 8;
  const ushort* wb = w2t + r16 * 256 + kg * 8;

#pragma unroll
  for (int s = 0; s < 8; s++) {
    short8 a = (s < 4) ? *(const short8*)(a0 + s * 32)
                       : *(const short8*)(a1 + (s - 4) * 32);
#pragma unroll
    for (int ct = 0; ct < 4; ct++) {
      short8 b = *(const short8*)(wb + ct * (16 * 256) + s * 32);
      acc[ct] = __builtin_amdgcn_mfma_f32_16x16x32_bf16(a, b, acc[ct], 0, 0, 0);
    }
  }

  float bb[4];
#pragma unroll
  for (int ct = 0; ct < 4; ct++) bb[ct] = b2[ct * 16 + r16];

#pragma unroll
  for (int r = 0; r < 4; r++) {
    float v[4];
#pragma unroll
    for (int ct = 0; ct < 4; ct++) v[ct] = acc[ct][r] + bb[ct];
    float m = fmaxf(fmaxf(v[0], v[1]), fmaxf(v[2], v[3]));
#pragma unroll
    for (int off = 1; off < 16; off <<= 1) m = fmaxf(m, __shfl_xor(m, off));
    float s = expf(v[0] - m) + expf(v[1] - m) + expf(v[2] - m) + expf(v[3] - m);
#pragma unroll
    for (int off = 1; off < 16; off <<= 1) s += __shfl_xor(s, off);
    float ls = logf(s);
    int n = node_base + kg * 4 + r;
    if (n < N) {
#pragma unroll
      for (int ct = 0; ct < 4; ct++)
        out[(long)n * 64 + ct * 16 + r16] = v[ct] - m - ls;
    }
  }
}

// ---------------------------------------------------------------------------
extern "C" void kernel_launch(void* const* d_in, const int* in_sizes, int n_in,
                              void* d_out, int out_size, void* d_ws, size_t ws_size,
                              hipStream_t stream) {
  const float* x   = (const float*)d_in[0];
  const void*  ei  = d_in[1];
  const float* W1l = (const float*)d_in[2];
  const float* b1  = (const float*)d_in[3];
  const float* W1r = (const float*)d_in[4];
  const float* W2l = (const float*)d_in[5];
  const float* b2  = (const float*)d_in[6];
  const float* W2r = (const float*)d_in[7];
  float* out = (float*)d_out;

  const int  N  = in_sizes[0] / D_FEAT;    // 100000
  const long E  = (long)in_sizes[1] / 2;   // 1600000
  const long NF = (long)N * D_FEAT;        // 12.8M
  const int  nbuck = (N + (1 << BSH) - 1) >> BSH;   // 782

  char* ws = (char*)d_ws;
  size_t off = 0;
  auto alloc = [&](size_t bytes) -> void* {
    void* p = ws + off;
    off = (off + bytes + 255) & ~(size_t)255;
    return p;
  };
  int*      bucketCnt = (int*)alloc(sizeof(int) * MAXB);
  int*      bucketPtr = (int*)alloc(sizeof(int) * (MAXB + 1));
  int*      bucketCur = (int*)alloc(sizeof(int) * MAXB);
  int*      rowptr    = (int*)alloc(sizeof(int) * (N + 1));
  int*      col       = (int*)alloc(sizeof(int) * E);
  uint32_t* packed    = (uint32_t*)alloc(sizeof(uint32_t) * E);
  float*    invd      = (float*)alloc(sizeof(float) * N);
  ushort*   xb        = (ushort*)alloc(sizeof(ushort) * NF);
  ushort*   aggb      = (ushort*)alloc(sizeof(ushort) * NF);
  ushort*   h1d       = (ushort*)alloc(sizeof(ushort) * NF);
  ushort*   w1t       = (ushort*)alloc(sizeof(ushort) * 128 * 256);
  ushort*   w2t       = (ushort*)alloc(sizeof(ushort) * 64 * 256);
  unsigned long long* maskb = (unsigned long long*)alloc(sizeof(unsigned long long) * 2 * N);
  int*      flag      = (int*)alloc(sizeof(int));

  const int chunkE = (int)((E + 255) / 256);   // edges per block, 256 blocks

  hipMemsetAsync(bucketCnt, 0, sizeof(int) * MAXB, stream);

  detect_kernel<<<1, 64, 0, stream>>>((const uint32_t*)ei, flag);
  convx_kernel<<<(int)((NF / 4 + 255) / 256), 256, 0, stream>>>((const float4*)x, xb, NF / 4);
  packw1_kernel<<<128, 256, 0, stream>>>(W1l, W1r, w1t);
  packw2_kernel<<<64, 256, 0, stream>>>(W2l, W2r, w2t);

  bucket_hist<<<256, 256, 0, stream>>>(ei, flag, bucketCnt, E, chunkE, nbuck);
  bucket_scan<<<1, 1024, 0, stream>>>(bucketCnt, bucketPtr, bucketCur, rowptr, N, nbuck, (int)E);
  bucket_scatter<<<256, 256, 0, stream>>>(ei, flag, bucketCur, packed, E, chunkE, nbuck);
  bucket_build<<<nbuck, 256, 0, stream>>>(packed, bucketPtr, col, rowptr, invd, N, nbuck);

  const int aggBlocks = (int)(((long)N * 64 + 255) / 256);
  const int gemmBlocks = (N + 63) / 64;

  agg_kernel<<<aggBlocks, 256, 0, stream>>>(xb, rowptr, col, invd, aggb, maskb, N);
  layer1_kernel<<<gemmBlocks, 256, 0, stream>>>(aggb, xb, w1t, b1, maskb, h1d, N);

  agg_kernel<<<aggBlocks, 256, 0, stream>>>(h1d, rowptr, col, invd, aggb, nullptr, N);
  layer2_kernel<<<gemmBlocks, 256, 0, stream>>>(aggb, h1d, w2t, b2, out, N);
}